// Round 4
// baseline (1847.909 us; speedup 1.0000x reference)
//
#include <hip/hip_runtime.h>
#include <hip/hip_bf16.h>

typedef __bf16 bf16x8 __attribute__((ext_vector_type(8)));
typedef float f32x4 __attribute__((ext_vector_type(4)));
typedef __hip_bfloat16 bf16;

static constexpr int NN = 8192;
static constexpr int DD = 128;
static constexpr int KTOP = 1638;   // int(0.2 * 8192)

// ---------------- input dtype detection ----------------
// If d_in[0] is float32 read as bf16, even-index elements are float low-halves:
// ~46% have exponent >= 0x8A (|v| > ~1e3). Genuine bf16 N(0,1) data: none.
__global__ void detect_dtype(const unsigned short* __restrict__ xin, int* __restrict__ flag) {
  __shared__ int cnt;
  if (threadIdx.x == 0) cnt = 0;
  __syncthreads();
  int c = 0;
  for (int i = threadIdx.x; i < 4096; i += 256) {
    int e = (xin[i] >> 7) & 0xFF;
    if (e >= 0x8A) ++c;
  }
  atomicAdd(&cnt, c);
  __syncthreads();
  if (threadIdx.x == 0) *flag = (cnt > 16) ? 1 : 0;
}

// ---------------- converters (dual dtype) ----------------

__global__ void cvt_to_f32(const void* __restrict__ in, float* __restrict__ out, int n,
                           const int* __restrict__ flag) {
  int isf32 = *flag;
  int i = blockIdx.x * blockDim.x + threadIdx.x;
  int stride = gridDim.x * blockDim.x;
  if (isf32) {
    const float* p = (const float*)in;
    for (; i < n; i += stride) out[i] = p[i];
  } else {
    const bf16* p = (const bf16*)in;
    for (; i < n; i += stride) out[i] = __bfloat162float(p[i]);
  }
}

// Wt[l][n][k] = W[l][k][n]  (so GEMM B-operand reads are contiguous in k)
__global__ void transpose_w(const void* __restrict__ W1, const void* __restrict__ W2,
                            bf16* __restrict__ Wt1, bf16* __restrict__ Wt2,
                            const int* __restrict__ flag) {
  int isf32 = *flag;
  int b = blockIdx.x;                      // 0,1 -> W1 l=0,1 ; 2,3 -> W2 l=0,1
  const void* srcv = (b < 2 ? W1 : W2);
  bf16* dst = (b < 2 ? Wt1 : Wt2) + (b & 1) * DD * DD;
  int off = (b & 1) * DD * DD;
  for (int f = threadIdx.x; f < DD * DD; f += blockDim.x) {
    int n = f >> 7, k = f & 127;
    float v;
    if (isf32) v = ((const float*)srcv)[off + k * DD + n];
    else       v = __bfloat162float(((const bf16*)srcv)[off + k * DD + n]);
    dst[n * DD + k] = __float2bfloat16(v);
  }
}

// per-row L2 normalize -> xnb (bf16), plus plain bf16 cast -> xb
__global__ void rownorm(const float* __restrict__ xf, bf16* __restrict__ xnb, bf16* __restrict__ xb) {
  int wave = threadIdx.x >> 6;
  int lane = threadIdx.x & 63;
  int row = blockIdx.x * 4 + wave;
  const float* xr = xf + (long)row * DD;
  float2 v = reinterpret_cast<const float2*>(xr)[lane];
  float s = v.x * v.x + v.y * v.y;
  for (int off = 1; off < 64; off <<= 1) s += __shfl_xor(s, off);
  float inv = 1.0f / (sqrtf(s) + 1e-8f);
  int c = lane * 2;
  xb[(long)row * DD + c]      = __float2bfloat16(v.x);
  xb[(long)row * DD + c + 1]  = __float2bfloat16(v.y);
  xnb[(long)row * DD + c]     = __float2bfloat16(v.x * inv);
  xnb[(long)row * DD + c + 1] = __float2bfloat16(v.y * inv);
}

// ---------------- rank-5 factorized Gaussian prior ----------------
// P_ij = exp(-(di-dj)^2/32) = a_i a_j exp(di dj/16),  a = exp(-d^2/32), d in [0,1)
// exp(z) ~= sum_t z^t/t!  (z <= 1/16, 5 terms -> err < 8e-9)
// P = sum_t c_t g_t g_t^T,  g_t(i) = a_i d_i^t,  c_t = 1/(16^t t!)

// block c<128: Mt[t*128+c] = sum_j g_t(j) * Yt1[c][j];  block c==128: Gt[t] = sum_j g_t(j)
__launch_bounds__(256)
__global__ void prior_reduce(const float* __restrict__ impf, const bf16* __restrict__ Yt1,
                             float* __restrict__ Mt, float* __restrict__ Gt) {
  __shared__ float red[5][4];
  int c = blockIdx.x;
  int tid = threadIdx.x;
  float s[5] = {0.f, 0.f, 0.f, 0.f, 0.f};
  bool hasY = (c < 128);
  const bf16* col = Yt1 + (long)(hasY ? c : 0) * NN;
  for (int j = tid; j < NN; j += 256) {
    float d = impf[j];
    float a = __expf(d * d * (-1.0f / 32.0f));
    float p = hasY ? a * __bfloat162float(col[j]) : a;
    #pragma unroll
    for (int t = 0; t < 5; ++t) { s[t] += p; p *= d; }
  }
  #pragma unroll
  for (int t = 0; t < 5; ++t)
    for (int off = 1; off < 64; off <<= 1) s[t] += __shfl_xor(s[t], off);
  int wave = tid >> 6, lane = tid & 63;
  if (lane == 0)
    #pragma unroll
    for (int t = 0; t < 5; ++t) red[t][wave] = s[t];
  __syncthreads();
  if (tid == 0) {
    #pragma unroll
    for (int t = 0; t < 5; ++t) {
      float v = red[t][0] + red[t][1] + red[t][2] + red[t][3];
      if (hasY) Mt[t * 128 + c] = v; else Gt[t] = v;
    }
  }
}

// per-row: pvec[i*8+t] = c_t g_t(i) / rowsumP(i)  (t<5), pvec[i*8+5] = 1/rowsumP(i)
__global__ void prior_vec(const float* __restrict__ impf, const float* __restrict__ Gt,
                          float* __restrict__ pvec) {
  int i = blockIdx.x * 256 + threadIdx.x;
  float d = impf[i];
  float a = __expf(d * d * (-1.0f / 32.0f));
  const float ct[5] = {1.0f, 1.0f / 16.0f, 1.0f / 512.0f, 1.0f / 24576.0f, 1.0f / 1572864.0f};
  float g[5];
  float p = a;
  #pragma unroll
  for (int t = 0; t < 5; ++t) { g[t] = ct[t] * p; p *= d; }
  float rs = 1.0f;  // + eye
  #pragma unroll
  for (int t = 0; t < 5; ++t) rs += g[t] * Gt[t];
  float inv = 1.0f / rs;
  #pragma unroll
  for (int t = 0; t < 5; ++t) pvec[i * 8 + t] = g[t] * inv;
  pvec[i * 8 + 5] = inv;
}

// ---------------- K=128 GEMM (MFMA): C[m][n] = sum_k A[m][k]*Bt[n][k] ----------------
__launch_bounds__(256)
__global__ void gemm_k128(const bf16* __restrict__ A, const bf16* __restrict__ Bt,
                          bf16* __restrict__ C, int ldc, int transC) {
  __shared__ bf16 lA[128][136];
  __shared__ bf16 lB[64][136];
  int tid = threadIdx.x;
  long rowA0 = (long)blockIdx.y * 128;
  long rowB0 = (long)blockIdx.x * 64;
  for (int i = 0; i < 8; ++i) {
    int f = tid + i * 256;
    int r = f >> 4, kg = f & 15;
    *reinterpret_cast<uint4*>(&lA[r][kg * 8]) =
        *reinterpret_cast<const uint4*>(A + (rowA0 + r) * DD + kg * 8);
  }
  for (int i = 0; i < 4; ++i) {
    int f = tid + i * 256;
    int r = f >> 4, kg = f & 15;
    *reinterpret_cast<uint4*>(&lB[r][kg * 8]) =
        *reinterpret_cast<const uint4*>(Bt + (rowB0 + r) * DD + kg * 8);
  }
  __syncthreads();
  int wave = tid >> 6, lane = tid & 63;
  int wm = (wave >> 1) * 64;
  int wn = (wave & 1) * 32;
  int quad = lane >> 4, l16 = lane & 15;
  f32x4 acc[4][2];
  #pragma unroll
  for (int mi = 0; mi < 4; ++mi)
    #pragma unroll
    for (int ni = 0; ni < 2; ++ni) acc[mi][ni] = {0.f, 0.f, 0.f, 0.f};
  #pragma unroll
  for (int ks = 0; ks < 4; ++ks) {
    int kb = ks * 32 + quad * 8;
    bf16x8 af[4], bfr[2];
    #pragma unroll
    for (int mi = 0; mi < 4; ++mi)
      af[mi] = *reinterpret_cast<const bf16x8*>(&lA[wm + mi * 16 + l16][kb]);
    #pragma unroll
    for (int ni = 0; ni < 2; ++ni)
      bfr[ni] = *reinterpret_cast<const bf16x8*>(&lB[wn + ni * 16 + l16][kb]);
    #pragma unroll
    for (int mi = 0; mi < 4; ++mi)
      #pragma unroll
      for (int ni = 0; ni < 2; ++ni)
        acc[mi][ni] = __builtin_amdgcn_mfma_f32_16x16x32_bf16(af[mi], bfr[ni], acc[mi][ni], 0, 0, 0);
  }
  #pragma unroll
  for (int mi = 0; mi < 4; ++mi)
    #pragma unroll
    for (int ni = 0; ni < 2; ++ni)
      #pragma unroll
      for (int r = 0; r < 4; ++r) {
        long row = rowA0 + wm + mi * 16 + quad * 4 + r;
        long col = rowB0 + wn + ni * 16 + l16;
        bf16 v = __float2bfloat16(acc[mi][ni][r]);
        if (transC) C[col * (long)ldc + row] = v;
        else        C[row * (long)ldc + col] = v;
      }
}

// ---------------- per-row top-k threshold + mask + rowsum ----------------
__launch_bounds__(256)
__global__ void topk_mask(bf16* __restrict__ Af, float* __restrict__ invRsF) {
  __shared__ float vals[NN];     // 32 KB
  __shared__ int hist[1024];     // 4 KB
  __shared__ float sred[4];
  __shared__ float s_thr;
  __shared__ int s_bin;
  int tid = threadIdx.x;
  long base = (long)blockIdx.x * NN;
  for (int i = 0; i < 4; ++i) {
    int f = tid + i * 256;
    uint4 v = *reinterpret_cast<const uint4*>(Af + base + (long)f * 8);
    const bf16* p = reinterpret_cast<const bf16*>(&v);
    #pragma unroll
    for (int e = 0; e < 8; ++e) vals[f * 8 + e] = __bfloat162float(p[e]);
  }
  const float LOV = -1.05f, HIV = 1.05f;
  const float bw1 = (HIV - LOV) / 1024.0f;
  const float sc1 = 1.0f / bw1;
  for (int i = tid; i < 1024; i += 256) hist[i] = 0;
  __syncthreads();
  for (int i = 0; i < 32; ++i) {
    float v = vals[tid + i * 256];
    int b = (int)((v - LOV) * sc1);
    b = b < 0 ? 0 : (b > 1023 ? 1023 : b);
    atomicAdd(&hist[b], 1);
  }
  __syncthreads();
  if (tid == 0) {
    int total = 0, bsel = 0;
    for (int b = 1023; b >= 0; --b) {
      int h = hist[b];
      if (total + h >= KTOP) { bsel = b; break; }
      total += h;
    }
    s_bin = bsel;
  }
  __syncthreads();
  int bsel = s_bin;
  float lo2 = LOV + bsel * bw1;
  float bw2 = bw1 / 1024.0f;
  float sc2 = 1.0f / bw2;
  __syncthreads();
  for (int i = tid; i < 1024; i += 256) hist[i] = 0;
  __syncthreads();
  for (int i = 0; i < 32; ++i) {
    float v = vals[tid + i * 256];
    int b = (int)((v - lo2) * sc2);
    b = b < 0 ? 0 : (b > 1023 ? 1023 : b);
    atomicAdd(&hist[b], 1);
  }
  __syncthreads();
  // Pass-2 histogram contains ALL row values (clamped into range), so the
  // KTOP-th-from-top cumulative count is the right selector here too.
  if (tid == 0) {
    int total = 0, b2 = 0;
    for (int b = 1023; b >= 0; --b) {
      int h = hist[b];
      if (total + h >= KTOP) { b2 = b; break; }
      total += h;
    }
    s_thr = lo2 + b2 * bw2;
  }
  __syncthreads();
  float thr = s_thr;
  float sum = 0.f;
  for (int i = 0; i < 4; ++i) {
    int f = tid + i * 256;
    bf16 tmp[8];
    #pragma unroll
    for (int e = 0; e < 8; ++e) {
      float v = vals[f * 8 + e];
      if (v >= thr) { sum += v; tmp[e] = __float2bfloat16(v); }
      else tmp[e] = __float2bfloat16(0.0f);
    }
    *reinterpret_cast<uint4*>(Af + base + (long)f * 8) = *reinterpret_cast<const uint4*>(tmp);
  }
  for (int off = 1; off < 64; off <<= 1) sum += __shfl_xor(sum, off);
  int wave = tid >> 6, lane = tid & 63;
  if (lane == 0) sred[wave] = sum;
  __syncthreads();
  if (tid == 0) invRsF[blockIdx.x] = 1.0f / (sred[0] + sred[1] + sred[2] + sred[3] + 1.0f);
}

// ---------------- fused  X' = leaky( prior_part + invRsF*(Af@Y2 + Y2) ) ----------------
// prior_part[i][c] = pvec[i][5]*Y1[i][c] + sum_t pvec[i][t]*Mt[t][c]
__launch_bounds__(256)
__global__ void fused_adj_gemm(const bf16* __restrict__ Af, const bf16* __restrict__ Yt2,
                               const bf16* __restrict__ Yt1,
                               const float* __restrict__ pvec, const float* __restrict__ Mt,
                               const float* __restrict__ invRsF,
                               float* __restrict__ Xout) {
  __shared__ bf16 lAf[32][72];
  __shared__ bf16 lY2[128][72];
  int tid = threadIdx.x;
  long row0 = (long)blockIdx.x * 32;
  int wave = tid >> 6, lane = tid & 63;
  int wm = (wave >> 1) * 16;   // 0 / 16
  int wn = (wave & 1) * 64;    // 0 / 64
  int quad = lane >> 4, l16 = lane & 15;
  f32x4 accF[4];
  #pragma unroll
  for (int ni = 0; ni < 4; ++ni) accF[ni] = {0.f, 0.f, 0.f, 0.f};
  for (int k0 = 0; k0 < NN; k0 += 64) {
    __syncthreads();
    {
      int r = tid >> 3, kg = tid & 7;   // 32 rows x 8 uint4
      *reinterpret_cast<uint4*>(&lAf[r][kg * 8]) =
          *reinterpret_cast<const uint4*>(Af + (row0 + r) * NN + k0 + kg * 8);
    }
    for (int i = 0; i < 4; ++i) {       // 128 cols x 8 uint4
      int f = tid + i * 256;
      int c = f >> 3, kg = f & 7;
      *reinterpret_cast<uint4*>(&lY2[c][kg * 8]) =
          *reinterpret_cast<const uint4*>(Yt2 + (long)c * NN + k0 + kg * 8);
    }
    __syncthreads();
    #pragma unroll
    for (int ks = 0; ks < 2; ++ks) {
      int kb = ks * 32 + quad * 8;
      bf16x8 afm = *reinterpret_cast<const bf16x8*>(&lAf[wm + l16][kb]);
      #pragma unroll
      for (int ni = 0; ni < 4; ++ni) {
        bf16x8 b2 = *reinterpret_cast<const bf16x8*>(&lY2[wn + ni * 16 + l16][kb]);
        accF[ni] = __builtin_amdgcn_mfma_f32_16x16x32_bf16(afm, b2, accF[ni], 0, 0, 0);
      }
    }
  }
  #pragma unroll
  for (int r = 0; r < 4; ++r) {
    long row = row0 + wm + quad * 4 + r;
    const float* pv = pvec + row * 8;
    float p0 = pv[0], p1 = pv[1], p2 = pv[2], p3 = pv[3], p4 = pv[4], pinv = pv[5];
    float irf = invRsF[row];
    #pragma unroll
    for (int ni = 0; ni < 4; ++ni) {
      int col = wn + ni * 16 + l16;
      float y1 = __bfloat162float(Yt1[(long)col * NN + row]);
      float y2 = __bfloat162float(Yt2[(long)col * NN + row]);
      float prior = pinv * y1 + p0 * Mt[col] + p1 * Mt[128 + col] + p2 * Mt[256 + col]
                  + p3 * Mt[384 + col] + p4 * Mt[512 + col];
      float v = prior + irf * (accF[ni][r] + y2);
      v = v > 0.f ? v : 0.01f * v;
      Xout[row * DD + col] = v;
    }
  }
}

// Output is float32 (the reference's output dtype — jax f32 math).
__global__ void final_out(const float* __restrict__ x2, const float* __restrict__ x1,
                          const float* __restrict__ impf, float* __restrict__ out) {
  int i = blockIdx.x * blockDim.x + threadIdx.x;
  if (i < NN * DD) out[i] = x2[i] + x1[i] * impf[i >> 7];
}

// ---------------- host ----------------

extern "C" void kernel_launch(void* const* d_in, const int* in_sizes, int n_in,
                              void* d_out, int out_size, void* d_ws, size_t ws_size,
                              hipStream_t stream) {
  const void* x_in   = d_in[0];
  const void* imp_in = d_in[1];
  const void* W1 = d_in[2];
  const void* W2 = d_in[3];
  float* out = (float*)d_out;

  char* ws = (char*)d_ws;
  size_t o = 0;
  auto alloc = [&](size_t bytes) { void* p = ws + o; o += (bytes + 511) & ~511ull; return p; };
  bf16*  Af   = (bf16*)alloc((size_t)NN * NN * 2);   // 134 MB (S, then masked feature adj)
  float* xf0  = (float*)alloc((size_t)NN * DD * 4);  // input x f32; reused as layer-1 output
  float* xf1  = (float*)alloc((size_t)NN * DD * 4);  // layer-0 output (= h for residual)
  bf16*  xnb  = (bf16*)alloc((size_t)NN * DD * 2);
  bf16*  xb   = (bf16*)alloc((size_t)NN * DD * 2);
  bf16*  Yt1  = (bf16*)alloc((size_t)NN * DD * 2);   // [128][8192] (x@W1)^T
  bf16*  Yt2  = (bf16*)alloc((size_t)NN * DD * 2);
  bf16*  Wt1  = (bf16*)alloc((size_t)2 * DD * DD * 2);
  bf16*  Wt2  = (bf16*)alloc((size_t)2 * DD * DD * 2);
  float* impf = (float*)alloc((size_t)NN * 4);
  float* pvec = (float*)alloc((size_t)NN * 8 * 4);
  float* Mt   = (float*)alloc((size_t)5 * 128 * 4);
  float* Gt   = (float*)alloc((size_t)8 * 4);
  float* invRsF = (float*)alloc((size_t)NN * 4);
  int*   dflag  = (int*)alloc(64);
  (void)ws_size; (void)n_in; (void)in_sizes; (void)out_size;

  detect_dtype<<<1, 256, 0, stream>>>((const unsigned short*)x_in, dflag);
  cvt_to_f32<<<4096, 256, 0, stream>>>(x_in, xf0, NN * DD, dflag);
  cvt_to_f32<<<32, 256, 0, stream>>>(imp_in, impf, NN, dflag);
  transpose_w<<<4, 256, 0, stream>>>(W1, W2, Wt1, Wt2, dflag);

  float* xcur = xf0;
  for (int l = 0; l < 2; ++l) {
    float* xnxt = (l == 0) ? xf1 : xf0;
    rownorm<<<NN / 4, 256, 0, stream>>>(xcur, xnb, xb);
    gemm_k128<<<dim3(2, 64), 256, 0, stream>>>(xb, Wt1 + l * DD * DD, Yt1, NN, 1);
    gemm_k128<<<dim3(2, 64), 256, 0, stream>>>(xb, Wt2 + l * DD * DD, Yt2, NN, 1);
    prior_reduce<<<129, 256, 0, stream>>>(impf, Yt1, Mt, Gt);
    prior_vec<<<NN / 256, 256, 0, stream>>>(impf, Gt, pvec);
    gemm_k128<<<dim3(NN / 64, NN / 128), 256, 0, stream>>>(xnb, xnb, Af, NN, 0);
    topk_mask<<<NN, 256, 0, stream>>>(Af, invRsF);
    fused_adj_gemm<<<NN / 32, 256, 0, stream>>>(Af, Yt2, Yt1, pvec, Mt, invRsF, xnxt);
    xcur = xnxt;
  }
  final_out<<<4096, 256, 0, stream>>>(xf0, xf1, impf, out);
}

// Round 5
// 601.790 us; speedup vs baseline: 3.0707x; 3.0707x over previous
//
#include <hip/hip_runtime.h>
#include <hip/hip_bf16.h>

typedef __bf16 bf16x8 __attribute__((ext_vector_type(8)));
typedef float f32x4 __attribute__((ext_vector_type(4)));
typedef __hip_bfloat16 bf16;

static constexpr int NN = 8192;
static constexpr int DD = 128;
static constexpr int KTOP = 1638;   // int(0.2 * 8192)

// ---------------- input dtype detection ----------------
// If d_in[0] is float32 read as bf16, even-index elements are float low-halves:
// ~46% have exponent >= 0x8A (|v| > ~1e3). Genuine bf16 N(0,1) data: none.
__global__ void detect_dtype(const unsigned short* __restrict__ xin, int* __restrict__ flag) {
  __shared__ int cnt;
  if (threadIdx.x == 0) cnt = 0;
  __syncthreads();
  int c = 0;
  for (int i = threadIdx.x; i < 4096; i += 256) {
    int e = (xin[i] >> 7) & 0xFF;
    if (e >= 0x8A) ++c;
  }
  atomicAdd(&cnt, c);
  __syncthreads();
  if (threadIdx.x == 0) *flag = (cnt > 16) ? 1 : 0;
}

// ---------------- converters (dual dtype) ----------------

__global__ void cvt_to_f32(const void* __restrict__ in, float* __restrict__ out, int n,
                           const int* __restrict__ flag) {
  int isf32 = *flag;
  int i = blockIdx.x * blockDim.x + threadIdx.x;
  int stride = gridDim.x * blockDim.x;
  if (isf32) {
    const float* p = (const float*)in;
    for (; i < n; i += stride) out[i] = p[i];
  } else {
    const bf16* p = (const bf16*)in;
    for (; i < n; i += stride) out[i] = __bfloat162float(p[i]);
  }
}

// Wt[l][n][k] = W[l][k][n]  (so GEMM B-operand reads are contiguous in k)
__global__ void transpose_w(const void* __restrict__ W1, const void* __restrict__ W2,
                            bf16* __restrict__ Wt1, bf16* __restrict__ Wt2,
                            const int* __restrict__ flag) {
  int isf32 = *flag;
  int b = blockIdx.x;                      // 0,1 -> W1 l=0,1 ; 2,3 -> W2 l=0,1
  const void* srcv = (b < 2 ? W1 : W2);
  bf16* dst = (b < 2 ? Wt1 : Wt2) + (b & 1) * DD * DD;
  int off = (b & 1) * DD * DD;
  for (int f = threadIdx.x; f < DD * DD; f += blockDim.x) {
    int n = f >> 7, k = f & 127;
    float v;
    if (isf32) v = ((const float*)srcv)[off + k * DD + n];
    else       v = __bfloat162float(((const bf16*)srcv)[off + k * DD + n]);
    dst[n * DD + k] = __float2bfloat16(v);
  }
}

// per-row L2 normalize -> xnb (bf16), plus plain bf16 cast -> xb
__global__ void rownorm(const float* __restrict__ xf, bf16* __restrict__ xnb, bf16* __restrict__ xb) {
  int wave = threadIdx.x >> 6;
  int lane = threadIdx.x & 63;
  int row = blockIdx.x * 4 + wave;
  const float* xr = xf + (long)row * DD;
  float2 v = reinterpret_cast<const float2*>(xr)[lane];
  float s = v.x * v.x + v.y * v.y;
  for (int off = 1; off < 64; off <<= 1) s += __shfl_xor(s, off);
  float inv = 1.0f / (sqrtf(s) + 1e-8f);
  int c = lane * 2;
  xb[(long)row * DD + c]      = __float2bfloat16(v.x);
  xb[(long)row * DD + c + 1]  = __float2bfloat16(v.y);
  xnb[(long)row * DD + c]     = __float2bfloat16(v.x * inv);
  xnb[(long)row * DD + c + 1] = __float2bfloat16(v.y * inv);
}

// ---------------- rank-5 factorized Gaussian prior ----------------
// P_ij = exp(-(di-dj)^2/32) = a_i a_j exp(di dj/16),  a = exp(-d^2/32), d in [0,1)
// exp(z) ~= sum_t z^t/t!  (z <= 1/16, 5 terms -> err < 8e-9)
// P = sum_t c_t g_t g_t^T,  g_t(i) = a_i d_i^t,  c_t = 1/(16^t t!)

// block c<128: Mt[t*128+c] = sum_j g_t(j) * Yt1[c][j];  block c==128: Gt[t] = sum_j g_t(j)
__launch_bounds__(256)
__global__ void prior_reduce(const float* __restrict__ impf, const bf16* __restrict__ Yt1,
                             float* __restrict__ Mt, float* __restrict__ Gt) {
  __shared__ float red[5][4];
  int c = blockIdx.x;
  int tid = threadIdx.x;
  float s[5] = {0.f, 0.f, 0.f, 0.f, 0.f};
  bool hasY = (c < 128);
  const bf16* col = Yt1 + (long)(hasY ? c : 0) * NN;
  for (int j = tid; j < NN; j += 256) {
    float d = impf[j];
    float a = __expf(d * d * (-1.0f / 32.0f));
    float p = hasY ? a * __bfloat162float(col[j]) : a;
    #pragma unroll
    for (int t = 0; t < 5; ++t) { s[t] += p; p *= d; }
  }
  #pragma unroll
  for (int t = 0; t < 5; ++t)
    for (int off = 1; off < 64; off <<= 1) s[t] += __shfl_xor(s[t], off);
  int wave = tid >> 6, lane = tid & 63;
  if (lane == 0)
    #pragma unroll
    for (int t = 0; t < 5; ++t) red[t][wave] = s[t];
  __syncthreads();
  if (tid == 0) {
    #pragma unroll
    for (int t = 0; t < 5; ++t) {
      float v = red[t][0] + red[t][1] + red[t][2] + red[t][3];
      if (hasY) Mt[t * 128 + c] = v; else Gt[t] = v;
    }
  }
}

// per-row: pvec[i*8+t] = c_t g_t(i) / rowsumP(i)  (t<5), pvec[i*8+5] = 1/rowsumP(i)
__global__ void prior_vec(const float* __restrict__ impf, const float* __restrict__ Gt,
                          float* __restrict__ pvec) {
  int i = blockIdx.x * 256 + threadIdx.x;
  float d = impf[i];
  float a = __expf(d * d * (-1.0f / 32.0f));
  const float ct[5] = {1.0f, 1.0f / 16.0f, 1.0f / 512.0f, 1.0f / 24576.0f, 1.0f / 1572864.0f};
  float g[5];
  float p = a;
  #pragma unroll
  for (int t = 0; t < 5; ++t) { g[t] = ct[t] * p; p *= d; }
  float rs = 1.0f;  // + eye
  #pragma unroll
  for (int t = 0; t < 5; ++t) rs += g[t] * Gt[t];
  float inv = 1.0f / rs;
  #pragma unroll
  for (int t = 0; t < 5; ++t) pvec[i * 8 + t] = g[t] * inv;
  pvec[i * 8 + 5] = inv;
}

// ---------------- K=128 GEMM (MFMA): C[m][n] = sum_k A[m][k]*Bt[n][k] ----------------
__launch_bounds__(256)
__global__ void gemm_k128(const bf16* __restrict__ A, const bf16* __restrict__ Bt,
                          bf16* __restrict__ C, int ldc, int transC) {
  __shared__ bf16 lA[128][136];
  __shared__ bf16 lB[64][136];
  int tid = threadIdx.x;
  long rowA0 = (long)blockIdx.y * 128;
  long rowB0 = (long)blockIdx.x * 64;
  for (int i = 0; i < 8; ++i) {
    int f = tid + i * 256;
    int r = f >> 4, kg = f & 15;
    *reinterpret_cast<uint4*>(&lA[r][kg * 8]) =
        *reinterpret_cast<const uint4*>(A + (rowA0 + r) * DD + kg * 8);
  }
  for (int i = 0; i < 4; ++i) {
    int f = tid + i * 256;
    int r = f >> 4, kg = f & 15;
    *reinterpret_cast<uint4*>(&lB[r][kg * 8]) =
        *reinterpret_cast<const uint4*>(Bt + (rowB0 + r) * DD + kg * 8);
  }
  __syncthreads();
  int wave = tid >> 6, lane = tid & 63;
  int wm = (wave >> 1) * 64;
  int wn = (wave & 1) * 32;
  int quad = lane >> 4, l16 = lane & 15;
  f32x4 acc[4][2];
  #pragma unroll
  for (int mi = 0; mi < 4; ++mi)
    #pragma unroll
    for (int ni = 0; ni < 2; ++ni) acc[mi][ni] = {0.f, 0.f, 0.f, 0.f};
  #pragma unroll
  for (int ks = 0; ks < 4; ++ks) {
    int kb = ks * 32 + quad * 8;
    bf16x8 af[4], bfr[2];
    #pragma unroll
    for (int mi = 0; mi < 4; ++mi)
      af[mi] = *reinterpret_cast<const bf16x8*>(&lA[wm + mi * 16 + l16][kb]);
    #pragma unroll
    for (int ni = 0; ni < 2; ++ni)
      bfr[ni] = *reinterpret_cast<const bf16x8*>(&lB[wn + ni * 16 + l16][kb]);
    #pragma unroll
    for (int mi = 0; mi < 4; ++mi)
      #pragma unroll
      for (int ni = 0; ni < 2; ++ni)
        acc[mi][ni] = __builtin_amdgcn_mfma_f32_16x16x32_bf16(af[mi], bfr[ni], acc[mi][ni], 0, 0, 0);
  }
  #pragma unroll
  for (int mi = 0; mi < 4; ++mi)
    #pragma unroll
    for (int ni = 0; ni < 2; ++ni)
      #pragma unroll
      for (int r = 0; r < 4; ++r) {
        long row = rowA0 + wm + mi * 16 + quad * 4 + r;
        long col = rowB0 + wn + ni * 16 + l16;
        bf16 v = __float2bfloat16(acc[mi][ni][r]);
        if (transC) C[col * (long)ldc + row] = v;
        else        C[row * (long)ldc + col] = v;
      }
}

// ---------------- per-row exact top-k threshold + mask + rowsum ----------------
// Register-resident radix binary search on order-preserving u16 keys of bf16.
// key(u) = (u & 0x8000) ? ~u : (u | 0x8000)  — monotone increasing with value.
// Finds K* = max K with count(key >= K) >= KTOP  ==  key of the KTOP-th largest
// value; mask keeps key >= K* (ties kept, matching reference S >= thr).
__launch_bounds__(256)
__global__ void topk_mask(bf16* __restrict__ Af, float* __restrict__ invRsF) {
  __shared__ int red[4];
  __shared__ float sred[4];
  int tid = threadIdx.x;
  int wave = tid >> 6, lane = tid & 63;
  long base = (long)blockIdx.x * NN;
  // load 32 elements/thread, convert to keys in registers
  int keys[32];
  #pragma unroll
  for (int i = 0; i < 4; ++i) {
    int f = tid + i * 256;
    uint4 v = *reinterpret_cast<const uint4*>(Af + base + (long)f * 8);
    const unsigned short* p = reinterpret_cast<const unsigned short*>(&v);
    #pragma unroll
    for (int e = 0; e < 8; ++e) {
      unsigned short u = p[e];
      keys[i * 8 + e] = (u & 0x8000) ? (unsigned short)~u : (unsigned short)(u | 0x8000);
    }
  }
  // 16-step bitwise binary search (all threads compute identical `cur`)
  int cur = 0;
  for (int bit = 15; bit >= 0; --bit) {
    int cand = cur | (1 << bit);
    int c = 0;
    #pragma unroll
    for (int i = 0; i < 32; ++i) c += (keys[i] >= cand) ? 1 : 0;
    for (int off = 1; off < 64; off <<= 1) c += __shfl_xor(c, off);
    if (lane == 0) red[wave] = c;
    __syncthreads();
    int tot = red[0] + red[1] + red[2] + red[3];
    __syncthreads();
    if (tot >= KTOP) cur = cand;
  }
  // mask + writeback + rowsum (reconstruct bf16 bits from keys)
  float sum = 0.f;
  #pragma unroll
  for (int i = 0; i < 4; ++i) {
    int f = tid + i * 256;
    unsigned short tmp[8];
    #pragma unroll
    for (int e = 0; e < 8; ++e) {
      int k = keys[i * 8 + e];
      unsigned short u = (k & 0x8000) ? (unsigned short)(k ^ 0x8000) : (unsigned short)~k;
      if (k >= cur) {
        unsigned int bits = ((unsigned int)u) << 16;
        float fv = __uint_as_float(bits);
        sum += fv;
        tmp[e] = u;
      } else {
        tmp[e] = 0;
      }
    }
    *reinterpret_cast<uint4*>(Af + base + (long)f * 8) = *reinterpret_cast<const uint4*>(tmp);
  }
  for (int off = 1; off < 64; off <<= 1) sum += __shfl_xor(sum, off);
  if (lane == 0) sred[wave] = sum;
  __syncthreads();
  if (tid == 0) invRsF[blockIdx.x] = 1.0f / (sred[0] + sred[1] + sred[2] + sred[3] + 1.0f);
}

// ---------------- fused  X' = leaky( prior_part + invRsF*(Af@Y2 + Y2) ) ----------------
// prior_part[i][c] = pvec[i][5]*Y1[i][c] + sum_t pvec[i][t]*Mt[t][c]
__launch_bounds__(256)
__global__ void fused_adj_gemm(const bf16* __restrict__ Af, const bf16* __restrict__ Yt2,
                               const bf16* __restrict__ Yt1,
                               const float* __restrict__ pvec, const float* __restrict__ Mt,
                               const float* __restrict__ invRsF,
                               float* __restrict__ Xout) {
  __shared__ bf16 lAf[32][72];
  __shared__ bf16 lY2[128][72];
  int tid = threadIdx.x;
  long row0 = (long)blockIdx.x * 32;
  int wave = tid >> 6, lane = tid & 63;
  int wm = (wave >> 1) * 16;   // 0 / 16
  int wn = (wave & 1) * 64;    // 0 / 64
  int quad = lane >> 4, l16 = lane & 15;
  f32x4 accF[4];
  #pragma unroll
  for (int ni = 0; ni < 4; ++ni) accF[ni] = {0.f, 0.f, 0.f, 0.f};
  for (int k0 = 0; k0 < NN; k0 += 64) {
    __syncthreads();
    {
      int r = tid >> 3, kg = tid & 7;   // 32 rows x 8 uint4
      *reinterpret_cast<uint4*>(&lAf[r][kg * 8]) =
          *reinterpret_cast<const uint4*>(Af + (row0 + r) * NN + k0 + kg * 8);
    }
    for (int i = 0; i < 4; ++i) {       // 128 cols x 8 uint4
      int f = tid + i * 256;
      int c = f >> 3, kg = f & 7;
      *reinterpret_cast<uint4*>(&lY2[c][kg * 8]) =
          *reinterpret_cast<const uint4*>(Yt2 + (long)c * NN + k0 + kg * 8);
    }
    __syncthreads();
    #pragma unroll
    for (int ks = 0; ks < 2; ++ks) {
      int kb = ks * 32 + quad * 8;
      bf16x8 afm = *reinterpret_cast<const bf16x8*>(&lAf[wm + l16][kb]);
      #pragma unroll
      for (int ni = 0; ni < 4; ++ni) {
        bf16x8 b2 = *reinterpret_cast<const bf16x8*>(&lY2[wn + ni * 16 + l16][kb]);
        accF[ni] = __builtin_amdgcn_mfma_f32_16x16x32_bf16(afm, b2, accF[ni], 0, 0, 0);
      }
    }
  }
  #pragma unroll
  for (int r = 0; r < 4; ++r) {
    long row = row0 + wm + quad * 4 + r;
    const float* pv = pvec + row * 8;
    float p0 = pv[0], p1 = pv[1], p2 = pv[2], p3 = pv[3], p4 = pv[4], pinv = pv[5];
    float irf = invRsF[row];
    #pragma unroll
    for (int ni = 0; ni < 4; ++ni) {
      int col = wn + ni * 16 + l16;
      float y1 = __bfloat162float(Yt1[(long)col * NN + row]);
      float y2 = __bfloat162float(Yt2[(long)col * NN + row]);
      float prior = pinv * y1 + p0 * Mt[col] + p1 * Mt[128 + col] + p2 * Mt[256 + col]
                  + p3 * Mt[384 + col] + p4 * Mt[512 + col];
      float v = prior + irf * (accF[ni][r] + y2);
      v = v > 0.f ? v : 0.01f * v;
      Xout[row * DD + col] = v;
    }
  }
}

// Output is float32 (the reference's output dtype — jax f32 math).
__global__ void final_out(const float* __restrict__ x2, const float* __restrict__ x1,
                          const float* __restrict__ impf, float* __restrict__ out) {
  int i = blockIdx.x * blockDim.x + threadIdx.x;
  if (i < NN * DD) out[i] = x2[i] + x1[i] * impf[i >> 7];
}

// ---------------- host ----------------

extern "C" void kernel_launch(void* const* d_in, const int* in_sizes, int n_in,
                              void* d_out, int out_size, void* d_ws, size_t ws_size,
                              hipStream_t stream) {
  const void* x_in   = d_in[0];
  const void* imp_in = d_in[1];
  const void* W1 = d_in[2];
  const void* W2 = d_in[3];
  float* out = (float*)d_out;

  char* ws = (char*)d_ws;
  size_t o = 0;
  auto alloc = [&](size_t bytes) { void* p = ws + o; o += (bytes + 511) & ~511ull; return p; };
  bf16*  Af   = (bf16*)alloc((size_t)NN * NN * 2);   // 134 MB (S, then masked feature adj)
  float* xf0  = (float*)alloc((size_t)NN * DD * 4);  // input x f32; reused as layer-1 output
  float* xf1  = (float*)alloc((size_t)NN * DD * 4);  // layer-0 output (= h for residual)
  bf16*  xnb  = (bf16*)alloc((size_t)NN * DD * 2);
  bf16*  xb   = (bf16*)alloc((size_t)NN * DD * 2);
  bf16*  Yt1  = (bf16*)alloc((size_t)NN * DD * 2);   // [128][8192] (x@W1)^T
  bf16*  Yt2  = (bf16*)alloc((size_t)NN * DD * 2);
  bf16*  Wt1  = (bf16*)alloc((size_t)2 * DD * DD * 2);
  bf16*  Wt2  = (bf16*)alloc((size_t)2 * DD * DD * 2);
  float* impf = (float*)alloc((size_t)NN * 4);
  float* pvec = (float*)alloc((size_t)NN * 8 * 4);
  float* Mt   = (float*)alloc((size_t)5 * 128 * 4);
  float* Gt   = (float*)alloc((size_t)8 * 4);
  float* invRsF = (float*)alloc((size_t)NN * 4);
  int*   dflag  = (int*)alloc(64);
  (void)ws_size; (void)n_in; (void)in_sizes; (void)out_size;

  detect_dtype<<<1, 256, 0, stream>>>((const unsigned short*)x_in, dflag);
  cvt_to_f32<<<4096, 256, 0, stream>>>(x_in, xf0, NN * DD, dflag);
  cvt_to_f32<<<32, 256, 0, stream>>>(imp_in, impf, NN, dflag);
  transpose_w<<<4, 256, 0, stream>>>(W1, W2, Wt1, Wt2, dflag);

  float* xcur = xf0;
  for (int l = 0; l < 2; ++l) {
    float* xnxt = (l == 0) ? xf1 : xf0;
    rownorm<<<NN / 4, 256, 0, stream>>>(xcur, xnb, xb);
    gemm_k128<<<dim3(2, 64), 256, 0, stream>>>(xb, Wt1 + l * DD * DD, Yt1, NN, 1);
    gemm_k128<<<dim3(2, 64), 256, 0, stream>>>(xb, Wt2 + l * DD * DD, Yt2, NN, 1);
    prior_reduce<<<129, 256, 0, stream>>>(impf, Yt1, Mt, Gt);
    prior_vec<<<NN / 256, 256, 0, stream>>>(impf, Gt, pvec);
    gemm_k128<<<dim3(NN / 64, NN / 128), 256, 0, stream>>>(xnb, xnb, Af, NN, 0);
    topk_mask<<<NN, 256, 0, stream>>>(Af, invRsF);
    fused_adj_gemm<<<NN / 32, 256, 0, stream>>>(Af, Yt2, Yt1, pvec, Mt, invRsF, xnxt);
    xcur = xnxt;
  }
  final_out<<<4096, 256, 0, stream>>>(xf0, xf1, impf, out);
}

// Round 6
// 533.801 us; speedup vs baseline: 3.4618x; 1.1274x over previous
//
#include <hip/hip_runtime.h>
#include <hip/hip_bf16.h>

typedef __bf16 bf16x8 __attribute__((ext_vector_type(8)));
typedef float f32x4 __attribute__((ext_vector_type(4)));
typedef __hip_bfloat16 bf16;

static constexpr int NN = 8192;
static constexpr int DD = 128;
static constexpr int KTOP = 1638;   // int(0.2 * 8192)
static constexpr int KSLICE = 4;    // split-K factor for the AV GEMM
static constexpr int KCH = NN / KSLICE;

// ---------------- input dtype detection ----------------
__global__ void detect_dtype(const unsigned short* __restrict__ xin, int* __restrict__ flag) {
  __shared__ int cnt;
  if (threadIdx.x == 0) cnt = 0;
  __syncthreads();
  int c = 0;
  for (int i = threadIdx.x; i < 4096; i += 256) {
    int e = (xin[i] >> 7) & 0xFF;
    if (e >= 0x8A) ++c;
  }
  atomicAdd(&cnt, c);
  __syncthreads();
  if (threadIdx.x == 0) *flag = (cnt > 16) ? 1 : 0;
}

// ---------------- converters (dual dtype) ----------------

__global__ void cvt_to_f32(const void* __restrict__ in, float* __restrict__ out, int n,
                           const int* __restrict__ flag) {
  int isf32 = *flag;
  int i = blockIdx.x * blockDim.x + threadIdx.x;
  int stride = gridDim.x * blockDim.x;
  if (isf32) {
    const float* p = (const float*)in;
    for (; i < n; i += stride) out[i] = p[i];
  } else {
    const bf16* p = (const bf16*)in;
    for (; i < n; i += stride) out[i] = __bfloat162float(p[i]);
  }
}

__global__ void transpose_w(const void* __restrict__ W1, const void* __restrict__ W2,
                            bf16* __restrict__ Wt1, bf16* __restrict__ Wt2,
                            const int* __restrict__ flag) {
  int isf32 = *flag;
  int b = blockIdx.x;
  const void* srcv = (b < 2 ? W1 : W2);
  bf16* dst = (b < 2 ? Wt1 : Wt2) + (b & 1) * DD * DD;
  int off = (b & 1) * DD * DD;
  for (int f = threadIdx.x; f < DD * DD; f += blockDim.x) {
    int n = f >> 7, k = f & 127;
    float v;
    if (isf32) v = ((const float*)srcv)[off + k * DD + n];
    else       v = __bfloat162float(((const bf16*)srcv)[off + k * DD + n]);
    dst[n * DD + k] = __float2bfloat16(v);
  }
}

// per-row L2 normalize -> xnb (bf16), plus plain bf16 cast -> xb
__global__ void rownorm(const float* __restrict__ xf, bf16* __restrict__ xnb, bf16* __restrict__ xb) {
  int wave = threadIdx.x >> 6;
  int lane = threadIdx.x & 63;
  int row = blockIdx.x * 4 + wave;
  const float* xr = xf + (long)row * DD;
  float2 v = reinterpret_cast<const float2*>(xr)[lane];
  float s = v.x * v.x + v.y * v.y;
  for (int off = 1; off < 64; off <<= 1) s += __shfl_xor(s, off);
  float inv = 1.0f / (sqrtf(s) + 1e-8f);
  int c = lane * 2;
  xb[(long)row * DD + c]      = __float2bfloat16(v.x);
  xb[(long)row * DD + c + 1]  = __float2bfloat16(v.y);
  xnb[(long)row * DD + c]     = __float2bfloat16(v.x * inv);
  xnb[(long)row * DD + c + 1] = __float2bfloat16(v.y * inv);
}

// ---------------- rank-5 factorized Gaussian prior ----------------
// P_ij = exp(-(di-dj)^2/32) = a_i a_j exp(di dj/16); 5-term Taylor of exp(z), z<=1/16.
__launch_bounds__(256)
__global__ void prior_reduce(const float* __restrict__ impf, const bf16* __restrict__ Yt1,
                             float* __restrict__ Mt, float* __restrict__ Gt) {
  __shared__ float red[5][4];
  int c = blockIdx.x;
  int tid = threadIdx.x;
  float s[5] = {0.f, 0.f, 0.f, 0.f, 0.f};
  bool hasY = (c < 128);
  const bf16* col = Yt1 + (long)(hasY ? c : 0) * NN;
  for (int j = tid; j < NN; j += 256) {
    float d = impf[j];
    float a = __expf(d * d * (-1.0f / 32.0f));
    float p = hasY ? a * __bfloat162float(col[j]) : a;
    #pragma unroll
    for (int t = 0; t < 5; ++t) { s[t] += p; p *= d; }
  }
  #pragma unroll
  for (int t = 0; t < 5; ++t)
    for (int off = 1; off < 64; off <<= 1) s[t] += __shfl_xor(s[t], off);
  int wave = tid >> 6, lane = tid & 63;
  if (lane == 0)
    #pragma unroll
    for (int t = 0; t < 5; ++t) red[t][wave] = s[t];
  __syncthreads();
  if (tid == 0) {
    #pragma unroll
    for (int t = 0; t < 5; ++t) {
      float v = red[t][0] + red[t][1] + red[t][2] + red[t][3];
      if (hasY) Mt[t * 128 + c] = v; else Gt[t] = v;
    }
  }
}

__global__ void prior_vec(const float* __restrict__ impf, const float* __restrict__ Gt,
                          float* __restrict__ pvec) {
  int i = blockIdx.x * 256 + threadIdx.x;
  float d = impf[i];
  float a = __expf(d * d * (-1.0f / 32.0f));
  const float ct[5] = {1.0f, 1.0f / 16.0f, 1.0f / 512.0f, 1.0f / 24576.0f, 1.0f / 1572864.0f};
  float g[5];
  float p = a;
  #pragma unroll
  for (int t = 0; t < 5; ++t) { g[t] = ct[t] * p; p *= d; }
  float rs = 1.0f;  // + eye
  #pragma unroll
  for (int t = 0; t < 5; ++t) rs += g[t] * Gt[t];
  float inv = 1.0f / rs;
  #pragma unroll
  for (int t = 0; t < 5; ++t) pvec[i * 8 + t] = g[t] * inv;
  pvec[i * 8 + 5] = inv;
}

// ---------------- K=128 GEMM (MFMA): C = A @ Bt^T ----------------
// transC: writes C[n][m] (ldc = NN). Cr (optional): row-major copy C[m][n], ld = DD.
__launch_bounds__(256)
__global__ void gemm_k128(const bf16* __restrict__ A, const bf16* __restrict__ Bt,
                          bf16* __restrict__ C, int ldc, int transC, bf16* __restrict__ Cr) {
  __shared__ bf16 lA[128][136];
  __shared__ bf16 lB[64][136];
  int tid = threadIdx.x;
  long rowA0 = (long)blockIdx.y * 128;
  long rowB0 = (long)blockIdx.x * 64;
  for (int i = 0; i < 8; ++i) {
    int f = tid + i * 256;
    int r = f >> 4, kg = f & 15;
    *reinterpret_cast<uint4*>(&lA[r][kg * 8]) =
        *reinterpret_cast<const uint4*>(A + (rowA0 + r) * DD + kg * 8);
  }
  for (int i = 0; i < 4; ++i) {
    int f = tid + i * 256;
    int r = f >> 4, kg = f & 15;
    *reinterpret_cast<uint4*>(&lB[r][kg * 8]) =
        *reinterpret_cast<const uint4*>(Bt + (rowB0 + r) * DD + kg * 8);
  }
  __syncthreads();
  int wave = tid >> 6, lane = tid & 63;
  int wm = (wave >> 1) * 64;
  int wn = (wave & 1) * 32;
  int quad = lane >> 4, l16 = lane & 15;
  f32x4 acc[4][2];
  #pragma unroll
  for (int mi = 0; mi < 4; ++mi)
    #pragma unroll
    for (int ni = 0; ni < 2; ++ni) acc[mi][ni] = {0.f, 0.f, 0.f, 0.f};
  #pragma unroll
  for (int ks = 0; ks < 4; ++ks) {
    int kb = ks * 32 + quad * 8;
    bf16x8 af[4], bfr[2];
    #pragma unroll
    for (int mi = 0; mi < 4; ++mi)
      af[mi] = *reinterpret_cast<const bf16x8*>(&lA[wm + mi * 16 + l16][kb]);
    #pragma unroll
    for (int ni = 0; ni < 2; ++ni)
      bfr[ni] = *reinterpret_cast<const bf16x8*>(&lB[wn + ni * 16 + l16][kb]);
    #pragma unroll
    for (int mi = 0; mi < 4; ++mi)
      #pragma unroll
      for (int ni = 0; ni < 2; ++ni)
        acc[mi][ni] = __builtin_amdgcn_mfma_f32_16x16x32_bf16(af[mi], bfr[ni], acc[mi][ni], 0, 0, 0);
  }
  #pragma unroll
  for (int mi = 0; mi < 4; ++mi)
    #pragma unroll
    for (int ni = 0; ni < 2; ++ni)
      #pragma unroll
      for (int r = 0; r < 4; ++r) {
        long row = rowA0 + wm + mi * 16 + quad * 4 + r;
        long col = rowB0 + wn + ni * 16 + l16;
        bf16 v = __float2bfloat16(acc[mi][ni][r]);
        if (transC) C[col * (long)ldc + row] = v;
        else        C[row * (long)ldc + col] = v;
        if (Cr)     Cr[row * DD + col] = v;
      }
}

// ---------------- per-row exact top-k threshold + rowsum (no writeback) ----------------
// Register-resident radix binary search on order-preserving u16 keys of bf16.
__launch_bounds__(256)
__global__ void topk_thresh(const bf16* __restrict__ S, unsigned short* __restrict__ kthr,
                            float* __restrict__ invRsF) {
  __shared__ int red[4];
  __shared__ float sred[4];
  int tid = threadIdx.x;
  int wave = tid >> 6, lane = tid & 63;
  long base = (long)blockIdx.x * NN;
  int keys[32];
  #pragma unroll
  for (int i = 0; i < 4; ++i) {
    int f = tid + i * 256;
    uint4 v = *reinterpret_cast<const uint4*>(S + base + (long)f * 8);
    const unsigned short* p = reinterpret_cast<const unsigned short*>(&v);
    #pragma unroll
    for (int e = 0; e < 8; ++e) {
      unsigned short u = p[e];
      keys[i * 8 + e] = (u & 0x8000) ? (unsigned short)~u : (unsigned short)(u | 0x8000);
    }
  }
  int cur = 0;
  for (int bit = 15; bit >= 0; --bit) {
    int cand = cur | (1 << bit);
    int c = 0;
    #pragma unroll
    for (int i = 0; i < 32; ++i) c += (keys[i] >= cand) ? 1 : 0;
    for (int off = 1; off < 64; off <<= 1) c += __shfl_xor(c, off);
    if (lane == 0) red[wave] = c;
    __syncthreads();
    int tot = red[0] + red[1] + red[2] + red[3];
    __syncthreads();
    if (tot >= KTOP) cur = cand;
  }
  float sum = 0.f;
  #pragma unroll
  for (int i = 0; i < 32; ++i) {
    int k = keys[i];
    if (k >= cur) {
      unsigned short u = (k & 0x8000) ? (unsigned short)(k ^ 0x8000) : (unsigned short)~k;
      sum += __uint_as_float(((unsigned int)u) << 16);
    }
  }
  for (int off = 1; off < 64; off <<= 1) sum += __shfl_xor(sum, off);
  if (lane == 0) sred[wave] = sum;
  __syncthreads();
  if (tid == 0) {
    invRsF[blockIdx.x] = 1.0f / (sred[0] + sred[1] + sred[2] + sred[3] + 1.0f);
    kthr[blockIdx.x] = (unsigned short)cur;
  }
}

// ---------------- split-K masked AV GEMM: Pacc[s] = (mask(S) @ Y2) over k-slice s ----
// grid (NN/32, KSLICE); mask applied on-the-fly during LDS staging (key >= kthr[row]).
__launch_bounds__(256)
__global__ void fused_av_partial(const bf16* __restrict__ S, const bf16* __restrict__ Yt2,
                                 const unsigned short* __restrict__ kthr,
                                 float* __restrict__ Pacc) {
  __shared__ bf16 lAf[32][72];
  __shared__ bf16 lY2[128][72];
  int tid = threadIdx.x;
  long row0 = (long)blockIdx.x * 32;
  long kbase = (long)blockIdx.y * KCH;
  int wave = tid >> 6, lane = tid & 63;
  int wm = (wave >> 1) * 16;   // 0 / 16
  int wn = (wave & 1) * 64;    // 0 / 64
  int quad = lane >> 4, l16 = lane & 15;
  int sr = tid >> 3, skg = tid & 7;          // staging coords: row, k-group
  int tk = kthr[row0 + sr];                  // per-thread row threshold key
  const bf16* srow = S + (row0 + sr) * (long)NN + kbase + skg * 8;
  f32x4 accF[4];
  #pragma unroll
  for (int ni = 0; ni < 4; ++ni) accF[ni] = {0.f, 0.f, 0.f, 0.f};
  for (int k0 = 0; k0 < KCH; k0 += 64) {
    __syncthreads();
    {
      uint4 v = *reinterpret_cast<const uint4*>(srow + k0);
      const unsigned short* p = reinterpret_cast<const unsigned short*>(&v);
      unsigned short m[8];
      #pragma unroll
      for (int e = 0; e < 8; ++e) {
        unsigned short u = p[e];
        int key = (u & 0x8000) ? (unsigned short)~u : (unsigned short)(u | 0x8000);
        m[e] = (key >= tk) ? u : (unsigned short)0;
      }
      *reinterpret_cast<uint4*>(&lAf[sr][skg * 8]) = *reinterpret_cast<const uint4*>(m);
    }
    for (int i = 0; i < 4; ++i) {       // 128 cols x 8 uint4
      int f = tid + i * 256;
      int c = f >> 3, kg = f & 7;
      *reinterpret_cast<uint4*>(&lY2[c][kg * 8]) =
          *reinterpret_cast<const uint4*>(Yt2 + (long)c * NN + kbase + k0 + kg * 8);
    }
    __syncthreads();
    #pragma unroll
    for (int ks = 0; ks < 2; ++ks) {
      int kb = ks * 32 + quad * 8;
      bf16x8 afm = *reinterpret_cast<const bf16x8*>(&lAf[wm + l16][kb]);
      #pragma unroll
      for (int ni = 0; ni < 4; ++ni) {
        bf16x8 b2 = *reinterpret_cast<const bf16x8*>(&lY2[wn + ni * 16 + l16][kb]);
        accF[ni] = __builtin_amdgcn_mfma_f32_16x16x32_bf16(afm, b2, accF[ni], 0, 0, 0);
      }
    }
  }
  float* out = Pacc + ((long)blockIdx.y * NN) * DD;
  #pragma unroll
  for (int ni = 0; ni < 4; ++ni)
    #pragma unroll
    for (int r = 0; r < 4; ++r) {
      long row = row0 + wm + quad * 4 + r;
      int col = wn + ni * 16 + l16;
      out[row * DD + col] = accF[ni][r];
    }
}

// ---------------- epilogue: reduce partials + prior + eye + leaky ----------------
__global__ void epilogue(const float* __restrict__ Pacc, const bf16* __restrict__ Yr1,
                         const bf16* __restrict__ Yr2, const float* __restrict__ pvec,
                         const float* __restrict__ Mt, const float* __restrict__ invRsF,
                         float* __restrict__ Xout) {
  int i = blockIdx.x * 256 + threadIdx.x;
  int row = i >> 7, col = i & 127;
  float acc = 0.f;
  #pragma unroll
  for (int s = 0; s < KSLICE; ++s) acc += Pacc[((long)s * NN + row) * DD + col];
  const float* pv = pvec + row * 8;
  float y1 = __bfloat162float(Yr1[i]);
  float y2 = __bfloat162float(Yr2[i]);
  float prior = pv[5] * y1 + pv[0] * Mt[col] + pv[1] * Mt[128 + col] + pv[2] * Mt[256 + col]
              + pv[3] * Mt[384 + col] + pv[4] * Mt[512 + col];
  float v = prior + invRsF[row] * (acc + y2);
  v = v > 0.f ? v : 0.01f * v;
  Xout[i] = v;
}

// Output is float32 (the reference's output dtype — jax f32 math).
__global__ void final_out(const float* __restrict__ x2, const float* __restrict__ x1,
                          const float* __restrict__ impf, float* __restrict__ out) {
  int i = blockIdx.x * blockDim.x + threadIdx.x;
  if (i < NN * DD) out[i] = x2[i] + x1[i] * impf[i >> 7];
}

// ---------------- host ----------------

extern "C" void kernel_launch(void* const* d_in, const int* in_sizes, int n_in,
                              void* d_out, int out_size, void* d_ws, size_t ws_size,
                              hipStream_t stream) {
  const void* x_in   = d_in[0];
  const void* imp_in = d_in[1];
  const void* W1 = d_in[2];
  const void* W2 = d_in[3];
  float* out = (float*)d_out;

  char* ws = (char*)d_ws;
  size_t o = 0;
  auto alloc = [&](size_t bytes) { void* p = ws + o; o += (bytes + 511) & ~511ull; return p; };
  bf16*  Af   = (bf16*)alloc((size_t)NN * NN * 2);    // 134 MB raw similarity S
  float* Pacc = (float*)alloc((size_t)KSLICE * NN * DD * 4);  // 16 MB split-K partials
  float* xf0  = (float*)alloc((size_t)NN * DD * 4);
  float* xf1  = (float*)alloc((size_t)NN * DD * 4);
  bf16*  xnb  = (bf16*)alloc((size_t)NN * DD * 2);
  bf16*  xb   = (bf16*)alloc((size_t)NN * DD * 2);
  bf16*  Yt1  = (bf16*)alloc((size_t)NN * DD * 2);    // [128][8192] (x@W1)^T
  bf16*  Yt2  = (bf16*)alloc((size_t)NN * DD * 2);
  bf16*  Yr1  = (bf16*)alloc((size_t)NN * DD * 2);    // [8192][128] row-major copies
  bf16*  Yr2  = (bf16*)alloc((size_t)NN * DD * 2);
  bf16*  Wt1  = (bf16*)alloc((size_t)2 * DD * DD * 2);
  bf16*  Wt2  = (bf16*)alloc((size_t)2 * DD * DD * 2);
  float* impf = (float*)alloc((size_t)NN * 4);
  float* pvec = (float*)alloc((size_t)NN * 8 * 4);
  float* Mt   = (float*)alloc((size_t)5 * 128 * 4);
  float* Gt   = (float*)alloc((size_t)8 * 4);
  float* invRsF = (float*)alloc((size_t)NN * 4);
  unsigned short* kthr = (unsigned short*)alloc((size_t)NN * 2);
  int*   dflag  = (int*)alloc(64);
  (void)ws_size; (void)n_in; (void)in_sizes; (void)out_size;

  detect_dtype<<<1, 256, 0, stream>>>((const unsigned short*)x_in, dflag);
  cvt_to_f32<<<4096, 256, 0, stream>>>(x_in, xf0, NN * DD, dflag);
  cvt_to_f32<<<32, 256, 0, stream>>>(imp_in, impf, NN, dflag);
  transpose_w<<<4, 256, 0, stream>>>(W1, W2, Wt1, Wt2, dflag);

  float* xcur = xf0;
  for (int l = 0; l < 2; ++l) {
    float* xnxt = (l == 0) ? xf1 : xf0;
    rownorm<<<NN / 4, 256, 0, stream>>>(xcur, xnb, xb);
    gemm_k128<<<dim3(2, 64), 256, 0, stream>>>(xb, Wt1 + l * DD * DD, Yt1, NN, 1, Yr1);
    gemm_k128<<<dim3(2, 64), 256, 0, stream>>>(xb, Wt2 + l * DD * DD, Yt2, NN, 1, Yr2);
    prior_reduce<<<129, 256, 0, stream>>>(impf, Yt1, Mt, Gt);
    prior_vec<<<NN / 256, 256, 0, stream>>>(impf, Gt, pvec);
    gemm_k128<<<dim3(NN / 64, NN / 128), 256, 0, stream>>>(xnb, xnb, Af, NN, 0, nullptr);
    topk_thresh<<<NN, 256, 0, stream>>>(Af, kthr, invRsF);
    fused_av_partial<<<dim3(NN / 32, KSLICE), 256, 0, stream>>>(Af, Yt2, kthr, Pacc);
    epilogue<<<NN * DD / 256, 256, 0, stream>>>(Pacc, Yr1, Yr2, pvec, Mt, invRsF, xnxt);
    xcur = xnxt;
  }
  final_out<<<4096, 256, 0, stream>>>(xf0, xf1, impf, out);
}

// Round 7
// 523.512 us; speedup vs baseline: 3.5298x; 1.0197x over previous
//
#include <hip/hip_runtime.h>
#include <hip/hip_bf16.h>

typedef __bf16 bf16x8 __attribute__((ext_vector_type(8)));
typedef float f32x4 __attribute__((ext_vector_type(4)));
typedef __hip_bfloat16 bf16;

static constexpr int NN = 8192;
static constexpr int DD = 128;
static constexpr int KTOP = 1638;   // int(0.2 * 8192)
static constexpr int KSLICE = 4;    // split-K factor for the AV GEMM
static constexpr int KCH = NN / KSLICE;

// ---------------- input dtype detection ----------------
__global__ void detect_dtype(const unsigned short* __restrict__ xin, int* __restrict__ flag) {
  __shared__ int cnt;
  if (threadIdx.x == 0) cnt = 0;
  __syncthreads();
  int c = 0;
  for (int i = threadIdx.x; i < 4096; i += 256) {
    int e = (xin[i] >> 7) & 0xFF;
    if (e >= 0x8A) ++c;
  }
  atomicAdd(&cnt, c);
  __syncthreads();
  if (threadIdx.x == 0) *flag = (cnt > 16) ? 1 : 0;
}

// ---------------- converters (dual dtype) ----------------

__global__ void cvt_to_f32(const void* __restrict__ in, float* __restrict__ out, int n,
                           const int* __restrict__ flag) {
  int isf32 = *flag;
  int i = blockIdx.x * blockDim.x + threadIdx.x;
  int stride = gridDim.x * blockDim.x;
  if (isf32) {
    const float* p = (const float*)in;
    for (; i < n; i += stride) out[i] = p[i];
  } else {
    const bf16* p = (const bf16*)in;
    for (; i < n; i += stride) out[i] = __bfloat162float(p[i]);
  }
}

__global__ void transpose_w(const void* __restrict__ W1, const void* __restrict__ W2,
                            bf16* __restrict__ Wt1, bf16* __restrict__ Wt2,
                            const int* __restrict__ flag) {
  int isf32 = *flag;
  int b = blockIdx.x;
  const void* srcv = (b < 2 ? W1 : W2);
  bf16* dst = (b < 2 ? Wt1 : Wt2) + (b & 1) * DD * DD;
  int off = (b & 1) * DD * DD;
  for (int f = threadIdx.x; f < DD * DD; f += blockDim.x) {
    int n = f >> 7, k = f & 127;
    float v;
    if (isf32) v = ((const float*)srcv)[off + k * DD + n];
    else       v = __bfloat162float(((const bf16*)srcv)[off + k * DD + n]);
    dst[n * DD + k] = __float2bfloat16(v);
  }
}

// per-row L2 normalize -> xnb (bf16), plus plain bf16 cast -> xb
__global__ void rownorm(const float* __restrict__ xf, bf16* __restrict__ xnb, bf16* __restrict__ xb) {
  int wave = threadIdx.x >> 6;
  int lane = threadIdx.x & 63;
  int row = blockIdx.x * 4 + wave;
  const float* xr = xf + (long)row * DD;
  float2 v = reinterpret_cast<const float2*>(xr)[lane];
  float s = v.x * v.x + v.y * v.y;
  for (int off = 1; off < 64; off <<= 1) s += __shfl_xor(s, off);
  float inv = 1.0f / (sqrtf(s) + 1e-8f);
  int c = lane * 2;
  xb[(long)row * DD + c]      = __float2bfloat16(v.x);
  xb[(long)row * DD + c + 1]  = __float2bfloat16(v.y);
  xnb[(long)row * DD + c]     = __float2bfloat16(v.x * inv);
  xnb[(long)row * DD + c + 1] = __float2bfloat16(v.y * inv);
}

// ---------------- rank-5 factorized Gaussian prior ----------------
// P_ij = exp(-(di-dj)^2/32) = a_i a_j exp(di dj/16); 5-term Taylor of exp(z), z<=1/16.
__launch_bounds__(256)
__global__ void prior_reduce(const float* __restrict__ impf, const bf16* __restrict__ Yt1,
                             float* __restrict__ Mt, float* __restrict__ Gt) {
  __shared__ float red[5][4];
  int c = blockIdx.x;
  int tid = threadIdx.x;
  float s[5] = {0.f, 0.f, 0.f, 0.f, 0.f};
  bool hasY = (c < 128);
  const bf16* col = Yt1 + (long)(hasY ? c : 0) * NN;
  for (int j = tid; j < NN; j += 256) {
    float d = impf[j];
    float a = __expf(d * d * (-1.0f / 32.0f));
    float p = hasY ? a * __bfloat162float(col[j]) : a;
    #pragma unroll
    for (int t = 0; t < 5; ++t) { s[t] += p; p *= d; }
  }
  #pragma unroll
  for (int t = 0; t < 5; ++t)
    for (int off = 1; off < 64; off <<= 1) s[t] += __shfl_xor(s[t], off);
  int wave = tid >> 6, lane = tid & 63;
  if (lane == 0)
    #pragma unroll
    for (int t = 0; t < 5; ++t) red[t][wave] = s[t];
  __syncthreads();
  if (tid == 0) {
    #pragma unroll
    for (int t = 0; t < 5; ++t) {
      float v = red[t][0] + red[t][1] + red[t][2] + red[t][3];
      if (hasY) Mt[t * 128 + c] = v; else Gt[t] = v;
    }
  }
}

__global__ void prior_vec(const float* __restrict__ impf, const float* __restrict__ Gt,
                          float* __restrict__ pvec) {
  int i = blockIdx.x * 256 + threadIdx.x;
  float d = impf[i];
  float a = __expf(d * d * (-1.0f / 32.0f));
  const float ct[5] = {1.0f, 1.0f / 16.0f, 1.0f / 512.0f, 1.0f / 24576.0f, 1.0f / 1572864.0f};
  float g[5];
  float p = a;
  #pragma unroll
  for (int t = 0; t < 5; ++t) { g[t] = ct[t] * p; p *= d; }
  float rs = 1.0f;  // + eye
  #pragma unroll
  for (int t = 0; t < 5; ++t) rs += g[t] * Gt[t];
  float inv = 1.0f / rs;
  #pragma unroll
  for (int t = 0; t < 5; ++t) pvec[i * 8 + t] = g[t] * inv;
  pvec[i * 8 + 5] = inv;
}

// ---------------- K=128 GEMM (MFMA): C = A @ Bt^T ----------------
// transC: writes C[n][m] (ldc = NN). Cr (optional): row-major copy C[m][n], ld = DD.
__launch_bounds__(256)
__global__ void gemm_k128(const bf16* __restrict__ A, const bf16* __restrict__ Bt,
                          bf16* __restrict__ C, int ldc, int transC, bf16* __restrict__ Cr) {
  __shared__ bf16 lA[128][136];
  __shared__ bf16 lB[64][136];
  int tid = threadIdx.x;
  long rowA0 = (long)blockIdx.y * 128;
  long rowB0 = (long)blockIdx.x * 64;
  for (int i = 0; i < 8; ++i) {
    int f = tid + i * 256;
    int r = f >> 4, kg = f & 15;
    *reinterpret_cast<uint4*>(&lA[r][kg * 8]) =
        *reinterpret_cast<const uint4*>(A + (rowA0 + r) * DD + kg * 8);
  }
  for (int i = 0; i < 4; ++i) {
    int f = tid + i * 256;
    int r = f >> 4, kg = f & 15;
    *reinterpret_cast<uint4*>(&lB[r][kg * 8]) =
        *reinterpret_cast<const uint4*>(Bt + (rowB0 + r) * DD + kg * 8);
  }
  __syncthreads();
  int wave = tid >> 6, lane = tid & 63;
  int wm = (wave >> 1) * 64;
  int wn = (wave & 1) * 32;
  int quad = lane >> 4, l16 = lane & 15;
  f32x4 acc[4][2];
  #pragma unroll
  for (int mi = 0; mi < 4; ++mi)
    #pragma unroll
    for (int ni = 0; ni < 2; ++ni) acc[mi][ni] = {0.f, 0.f, 0.f, 0.f};
  #pragma unroll
  for (int ks = 0; ks < 4; ++ks) {
    int kb = ks * 32 + quad * 8;
    bf16x8 af[4], bfr[2];
    #pragma unroll
    for (int mi = 0; mi < 4; ++mi)
      af[mi] = *reinterpret_cast<const bf16x8*>(&lA[wm + mi * 16 + l16][kb]);
    #pragma unroll
    for (int ni = 0; ni < 2; ++ni)
      bfr[ni] = *reinterpret_cast<const bf16x8*>(&lB[wn + ni * 16 + l16][kb]);
    #pragma unroll
    for (int mi = 0; mi < 4; ++mi)
      #pragma unroll
      for (int ni = 0; ni < 2; ++ni)
        acc[mi][ni] = __builtin_amdgcn_mfma_f32_16x16x32_bf16(af[mi], bfr[ni], acc[mi][ni], 0, 0, 0);
  }
  #pragma unroll
  for (int mi = 0; mi < 4; ++mi)
    #pragma unroll
    for (int ni = 0; ni < 2; ++ni)
      #pragma unroll
      for (int r = 0; r < 4; ++r) {
        long row = rowA0 + wm + mi * 16 + quad * 4 + r;
        long col = rowB0 + wn + ni * 16 + l16;
        bf16 v = __float2bfloat16(acc[mi][ni][r]);
        if (transC) C[col * (long)ldc + row] = v;
        else        C[row * (long)ldc + col] = v;
        if (Cr)     Cr[row * DD + col] = v;
      }
}

// ---------------- per-row exact top-k threshold + rowsum (ballot counting) ----------------
// Radix binary search on order-preserving u16 keys of bf16; count(key>=cand) via
// wave ballot (v_cmp -> SGPR pair) + scalar popcount, so the VALU cost is one
// v_cmp per key per iteration and the popcount/accumulate runs on the scalar pipe.
__launch_bounds__(256)
__global__ void topk_thresh(const bf16* __restrict__ S, unsigned short* __restrict__ kthr,
                            float* __restrict__ invRsF) {
  __shared__ int red[4];
  __shared__ float sred[4];
  int tid = threadIdx.x;
  int wave = tid >> 6, lane = tid & 63;
  long base = (long)blockIdx.x * NN;
  int keys[32];
  #pragma unroll
  for (int i = 0; i < 4; ++i) {
    int f = tid + i * 256;
    uint4 v = *reinterpret_cast<const uint4*>(S + base + (long)f * 8);
    const unsigned short* p = reinterpret_cast<const unsigned short*>(&v);
    #pragma unroll
    for (int e = 0; e < 8; ++e) {
      unsigned short u = p[e];
      keys[i * 8 + e] = (u & 0x8000) ? (unsigned short)~u : (unsigned short)(u | 0x8000);
    }
  }
  int cur = 0;
  #pragma unroll
  for (int bit = 15; bit >= 0; --bit) {
    int cand = cur | (1 << bit);
    int c = 0;
    #pragma unroll
    for (int i = 0; i < 32; ++i)
      c += (int)__popcll(__ballot(keys[i] >= cand));
    if (lane == 0) red[wave] = c;   // c is wave-uniform
    __syncthreads();
    int tot = red[0] + red[1] + red[2] + red[3];
    __syncthreads();
    if (tot >= KTOP) cur = cand;
  }
  float sum = 0.f;
  #pragma unroll
  for (int i = 0; i < 32; ++i) {
    int k = keys[i];
    if (k >= cur) {
      unsigned short u = (k & 0x8000) ? (unsigned short)(k ^ 0x8000) : (unsigned short)~k;
      sum += __uint_as_float(((unsigned int)u) << 16);
    }
  }
  for (int off = 1; off < 64; off <<= 1) sum += __shfl_xor(sum, off);
  if (lane == 0) sred[wave] = sum;
  __syncthreads();
  if (tid == 0) {
    invRsF[blockIdx.x] = 1.0f / (sred[0] + sred[1] + sred[2] + sred[3] + 1.0f);
    kthr[blockIdx.x] = (unsigned short)cur;
  }
}

// ---------------- split-K masked AV GEMM: Pacc[s] = (mask(S) @ Y2) over k-slice s ----
// grid (NN/32, KSLICE); mask applied on-the-fly during LDS staging (key >= kthr[row]).
__launch_bounds__(256)
__global__ void fused_av_partial(const bf16* __restrict__ S, const bf16* __restrict__ Yt2,
                                 const unsigned short* __restrict__ kthr,
                                 float* __restrict__ Pacc) {
  __shared__ bf16 lAf[32][72];
  __shared__ bf16 lY2[128][72];
  int tid = threadIdx.x;
  long row0 = (long)blockIdx.x * 32;
  long kbase = (long)blockIdx.y * KCH;
  int wave = tid >> 6, lane = tid & 63;
  int wm = (wave >> 1) * 16;   // 0 / 16
  int wn = (wave & 1) * 64;    // 0 / 64
  int quad = lane >> 4, l16 = lane & 15;
  int sr = tid >> 3, skg = tid & 7;          // staging coords: row, k-group
  int tk = kthr[row0 + sr];                  // per-thread row threshold key
  const bf16* srow = S + (row0 + sr) * (long)NN + kbase + skg * 8;
  f32x4 accF[4];
  #pragma unroll
  for (int ni = 0; ni < 4; ++ni) accF[ni] = {0.f, 0.f, 0.f, 0.f};
  for (int k0 = 0; k0 < KCH; k0 += 64) {
    __syncthreads();
    {
      uint4 v = *reinterpret_cast<const uint4*>(srow + k0);
      const unsigned short* p = reinterpret_cast<const unsigned short*>(&v);
      unsigned short m[8];
      #pragma unroll
      for (int e = 0; e < 8; ++e) {
        unsigned short u = p[e];
        int key = (u & 0x8000) ? (unsigned short)~u : (unsigned short)(u | 0x8000);
        m[e] = (key >= tk) ? u : (unsigned short)0;
      }
      *reinterpret_cast<uint4*>(&lAf[sr][skg * 8]) = *reinterpret_cast<const uint4*>(m);
    }
    for (int i = 0; i < 4; ++i) {       // 128 cols x 8 uint4
      int f = tid + i * 256;
      int c = f >> 3, kg = f & 7;
      *reinterpret_cast<uint4*>(&lY2[c][kg * 8]) =
          *reinterpret_cast<const uint4*>(Yt2 + (long)c * NN + kbase + k0 + kg * 8);
    }
    __syncthreads();
    #pragma unroll
    for (int ks = 0; ks < 2; ++ks) {
      int kb = ks * 32 + quad * 8;
      bf16x8 afm = *reinterpret_cast<const bf16x8*>(&lAf[wm + l16][kb]);
      #pragma unroll
      for (int ni = 0; ni < 4; ++ni) {
        bf16x8 b2 = *reinterpret_cast<const bf16x8*>(&lY2[wn + ni * 16 + l16][kb]);
        accF[ni] = __builtin_amdgcn_mfma_f32_16x16x32_bf16(afm, b2, accF[ni], 0, 0, 0);
      }
    }
  }
  float* out = Pacc + ((long)blockIdx.y * NN) * DD;
  #pragma unroll
  for (int ni = 0; ni < 4; ++ni)
    #pragma unroll
    for (int r = 0; r < 4; ++r) {
      long row = row0 + wm + quad * 4 + r;
      int col = wn + ni * 16 + l16;
      out[row * DD + col] = accF[ni][r];
    }
}

// ---------------- epilogue: reduce partials + prior + eye + leaky ----------------
__global__ void epilogue(const float* __restrict__ Pacc, const bf16* __restrict__ Yr1,
                         const bf16* __restrict__ Yr2, const float* __restrict__ pvec,
                         const float* __restrict__ Mt, const float* __restrict__ invRsF,
                         float* __restrict__ Xout) {
  int i = blockIdx.x * 256 + threadIdx.x;
  int row = i >> 7, col = i & 127;
  float acc = 0.f;
  #pragma unroll
  for (int s = 0; s < KSLICE; ++s) acc += Pacc[((long)s * NN + row) * DD + col];
  const float* pv = pvec + row * 8;
  float y1 = __bfloat162float(Yr1[i]);
  float y2 = __bfloat162float(Yr2[i]);
  float prior = pv[5] * y1 + pv[0] * Mt[col] + pv[1] * Mt[128 + col] + pv[2] * Mt[256 + col]
              + pv[3] * Mt[384 + col] + pv[4] * Mt[512 + col];
  float v = prior + invRsF[row] * (acc + y2);
  v = v > 0.f ? v : 0.01f * v;
  Xout[i] = v;
}

// Output is float32 (the reference's output dtype — jax f32 math).
__global__ void final_out(const float* __restrict__ x2, const float* __restrict__ x1,
                          const float* __restrict__ impf, float* __restrict__ out) {
  int i = blockIdx.x * blockDim.x + threadIdx.x;
  if (i < NN * DD) out[i] = x2[i] + x1[i] * impf[i >> 7];
}

// ---------------- host ----------------

extern "C" void kernel_launch(void* const* d_in, const int* in_sizes, int n_in,
                              void* d_out, int out_size, void* d_ws, size_t ws_size,
                              hipStream_t stream) {
  const void* x_in   = d_in[0];
  const void* imp_in = d_in[1];
  const void* W1 = d_in[2];
  const void* W2 = d_in[3];
  float* out = (float*)d_out;

  char* ws = (char*)d_ws;
  size_t o = 0;
  auto alloc = [&](size_t bytes) { void* p = ws + o; o += (bytes + 511) & ~511ull; return p; };
  bf16*  Af   = (bf16*)alloc((size_t)NN * NN * 2);    // 134 MB raw similarity S
  float* Pacc = (float*)alloc((size_t)KSLICE * NN * DD * 4);  // 16 MB split-K partials
  float* xf0  = (float*)alloc((size_t)NN * DD * 4);
  float* xf1  = (float*)alloc((size_t)NN * DD * 4);
  bf16*  xnb  = (bf16*)alloc((size_t)NN * DD * 2);
  bf16*  xb   = (bf16*)alloc((size_t)NN * DD * 2);
  bf16*  Yt1  = (bf16*)alloc((size_t)NN * DD * 2);    // [128][8192] (x@W1)^T
  bf16*  Yt2  = (bf16*)alloc((size_t)NN * DD * 2);
  bf16*  Yr1  = (bf16*)alloc((size_t)NN * DD * 2);    // [8192][128] row-major copies
  bf16*  Yr2  = (bf16*)alloc((size_t)NN * DD * 2);
  bf16*  Wt1  = (bf16*)alloc((size_t)2 * DD * DD * 2);
  bf16*  Wt2  = (bf16*)alloc((size_t)2 * DD * DD * 2);
  float* impf = (float*)alloc((size_t)NN * 4);
  float* pvec = (float*)alloc((size_t)NN * 8 * 4);
  float* Mt   = (float*)alloc((size_t)5 * 128 * 4);
  float* Gt   = (float*)alloc((size_t)8 * 4);
  float* invRsF = (float*)alloc((size_t)NN * 4);
  unsigned short* kthr = (unsigned short*)alloc((size_t)NN * 2);
  int*   dflag  = (int*)alloc(64);
  (void)ws_size; (void)n_in; (void)in_sizes; (void)out_size;

  detect_dtype<<<1, 256, 0, stream>>>((const unsigned short*)x_in, dflag);
  cvt_to_f32<<<4096, 256, 0, stream>>>(x_in, xf0, NN * DD, dflag);
  cvt_to_f32<<<32, 256, 0, stream>>>(imp_in, impf, NN, dflag);
  transpose_w<<<4, 256, 0, stream>>>(W1, W2, Wt1, Wt2, dflag);

  float* xcur = xf0;
  for (int l = 0; l < 2; ++l) {
    float* xnxt = (l == 0) ? xf1 : xf0;
    rownorm<<<NN / 4, 256, 0, stream>>>(xcur, xnb, xb);
    gemm_k128<<<dim3(2, 64), 256, 0, stream>>>(xb, Wt1 + l * DD * DD, Yt1, NN, 1, Yr1);
    gemm_k128<<<dim3(2, 64), 256, 0, stream>>>(xb, Wt2 + l * DD * DD, Yt2, NN, 1, Yr2);
    prior_reduce<<<129, 256, 0, stream>>>(impf, Yt1, Mt, Gt);
    prior_vec<<<NN / 256, 256, 0, stream>>>(impf, Gt, pvec);
    gemm_k128<<<dim3(NN / 64, NN / 128), 256, 0, stream>>>(xnb, xnb, Af, NN, 0, nullptr);
    topk_thresh<<<NN, 256, 0, stream>>>(Af, kthr, invRsF);
    fused_av_partial<<<dim3(NN / 32, KSLICE), 256, 0, stream>>>(Af, Yt2, kthr, Pacc);
    epilogue<<<NN * DD / 256, 256, 0, stream>>>(Pacc, Yr1, Yr2, pvec, Mt, invRsF, xnxt);
    xcur = xnxt;
  }
  final_out<<<4096, 256, 0, stream>>>(xf0, xf1, impf, out);
}

// Round 8
// 494.504 us; speedup vs baseline: 3.7369x; 1.0587x over previous
//
#include <hip/hip_runtime.h>
#include <hip/hip_bf16.h>

typedef __bf16 bf16x8 __attribute__((ext_vector_type(8)));
typedef float f32x4 __attribute__((ext_vector_type(4)));
typedef __hip_bfloat16 bf16;

static constexpr int NN = 8192;
static constexpr int DD = 128;
static constexpr int KTOP = 1638;   // int(0.2 * 8192)
static constexpr int KSLICE = 4;    // split-K factor for the AV GEMM
static constexpr int KCH = NN / KSLICE;

// Wave-wide mask of (a >= b) without the bool->int->ballot double compare:
// lowers to a single v_cmp_ge_u32 writing an SGPR pair. 35 = ICMP_UGE.
#if __has_builtin(__builtin_amdgcn_uicmp)
#define WAVE_GE_MASK(a, b) __builtin_amdgcn_uicmp((int)(a), (int)(b), 35)
#else
#define WAVE_GE_MASK(a, b) __ballot((unsigned)(a) >= (unsigned)(b))
#endif

// ---------------- input dtype detection ----------------
__global__ void detect_dtype(const unsigned short* __restrict__ xin, int* __restrict__ flag) {
  __shared__ int cnt;
  if (threadIdx.x == 0) cnt = 0;
  __syncthreads();
  int c = 0;
  for (int i = threadIdx.x; i < 4096; i += 256) {
    int e = (xin[i] >> 7) & 0xFF;
    if (e >= 0x8A) ++c;
  }
  atomicAdd(&cnt, c);
  __syncthreads();
  if (threadIdx.x == 0) *flag = (cnt > 16) ? 1 : 0;
}

// ---------------- merged prep: cvt x, cvt imp, transpose W (dual dtype) ----------------
__global__ void prep(const void* __restrict__ x_in, const void* __restrict__ imp_in,
                     const void* __restrict__ W1, const void* __restrict__ W2,
                     float* __restrict__ xf, float* __restrict__ impf,
                     bf16* __restrict__ Wt1, bf16* __restrict__ Wt2,
                     const int* __restrict__ flag) {
  int isf32 = *flag;
  int b = blockIdx.x;
  if (b < 4096) {
    int i = b * 256 + threadIdx.x;
    xf[i] = isf32 ? ((const float*)x_in)[i] : __bfloat162float(((const bf16*)x_in)[i]);
  } else if (b == 4096) {
    for (int i = threadIdx.x; i < NN; i += 256)
      impf[i] = isf32 ? ((const float*)imp_in)[i] : __bfloat162float(((const bf16*)imp_in)[i]);
  } else {
    int w = b - 4097;                 // 0,1 -> W1 l=0,1 ; 2,3 -> W2 l=0,1
    const void* srcv = (w < 2 ? W1 : W2);
    bf16* dst = (w < 2 ? Wt1 : Wt2) + (w & 1) * DD * DD;
    int off = (w & 1) * DD * DD;
    for (int f = threadIdx.x; f < DD * DD; f += 256) {
      int n = f >> 7, k = f & 127;
      float v = isf32 ? ((const float*)srcv)[off + k * DD + n]
                      : __bfloat162float(((const bf16*)srcv)[off + k * DD + n]);
      dst[n * DD + k] = __float2bfloat16(v);
    }
  }
}

// per-row L2 normalize -> xnb (bf16), plus plain bf16 cast -> xb
__global__ void rownorm(const float* __restrict__ xf, bf16* __restrict__ xnb, bf16* __restrict__ xb) {
  int wave = threadIdx.x >> 6;
  int lane = threadIdx.x & 63;
  int row = blockIdx.x * 4 + wave;
  const float* xr = xf + (long)row * DD;
  float2 v = reinterpret_cast<const float2*>(xr)[lane];
  float s = v.x * v.x + v.y * v.y;
  for (int off = 1; off < 64; off <<= 1) s += __shfl_xor(s, off);
  float inv = 1.0f / (sqrtf(s) + 1e-8f);
  int c = lane * 2;
  xb[(long)row * DD + c]      = __float2bfloat16(v.x);
  xb[(long)row * DD + c + 1]  = __float2bfloat16(v.y);
  xnb[(long)row * DD + c]     = __float2bfloat16(v.x * inv);
  xnb[(long)row * DD + c + 1] = __float2bfloat16(v.y * inv);
}

// ---------------- rank-5 factorized Gaussian prior ----------------
// P_ij = exp(-(di-dj)^2/32) = a_i a_j exp(di dj/16); 5-term Taylor of exp(z), z<=1/16.
__launch_bounds__(256)
__global__ void prior_reduce(const float* __restrict__ impf, const bf16* __restrict__ Yt1,
                             float* __restrict__ Mt, float* __restrict__ Gt) {
  __shared__ float red[5][4];
  int c = blockIdx.x;
  int tid = threadIdx.x;
  float s[5] = {0.f, 0.f, 0.f, 0.f, 0.f};
  bool hasY = (c < 128);
  const bf16* col = Yt1 + (long)(hasY ? c : 0) * NN;
  for (int j = tid; j < NN; j += 256) {
    float d = impf[j];
    float a = __expf(d * d * (-1.0f / 32.0f));
    float p = hasY ? a * __bfloat162float(col[j]) : a;
    #pragma unroll
    for (int t = 0; t < 5; ++t) { s[t] += p; p *= d; }
  }
  #pragma unroll
  for (int t = 0; t < 5; ++t)
    for (int off = 1; off < 64; off <<= 1) s[t] += __shfl_xor(s[t], off);
  int wave = tid >> 6, lane = tid & 63;
  if (lane == 0)
    #pragma unroll
    for (int t = 0; t < 5; ++t) red[t][wave] = s[t];
  __syncthreads();
  if (tid == 0) {
    #pragma unroll
    for (int t = 0; t < 5; ++t) {
      float v = red[t][0] + red[t][1] + red[t][2] + red[t][3];
      if (hasY) Mt[t * 128 + c] = v; else Gt[t] = v;
    }
  }
}

__global__ void prior_vec(const float* __restrict__ impf, const float* __restrict__ Gt,
                          float* __restrict__ pvec) {
  int i = blockIdx.x * 256 + threadIdx.x;
  float d = impf[i];
  float a = __expf(d * d * (-1.0f / 32.0f));
  const float ct[5] = {1.0f, 1.0f / 16.0f, 1.0f / 512.0f, 1.0f / 24576.0f, 1.0f / 1572864.0f};
  float g[5];
  float p = a;
  #pragma unroll
  for (int t = 0; t < 5; ++t) { g[t] = ct[t] * p; p *= d; }
  float rs = 1.0f;  // + eye
  #pragma unroll
  for (int t = 0; t < 5; ++t) rs += g[t] * Gt[t];
  float inv = 1.0f / rs;
  #pragma unroll
  for (int t = 0; t < 5; ++t) pvec[i * 8 + t] = g[t] * inv;
  pvec[i * 8 + 5] = inv;
}

// ---------------- K=128 GEMM (MFMA): C = A @ Bt^T ----------------
// transC: writes C[n][m] (ldc = NN). Cr (optional): row-major copy C[m][n], ld = DD.
__launch_bounds__(256)
__global__ void gemm_k128(const bf16* __restrict__ A, const bf16* __restrict__ Bt,
                          bf16* __restrict__ C, int ldc, int transC, bf16* __restrict__ Cr) {
  __shared__ bf16 lA[128][136];
  __shared__ bf16 lB[64][136];
  int tid = threadIdx.x;
  long rowA0 = (long)blockIdx.y * 128;
  long rowB0 = (long)blockIdx.x * 64;
  for (int i = 0; i < 8; ++i) {
    int f = tid + i * 256;
    int r = f >> 4, kg = f & 15;
    *reinterpret_cast<uint4*>(&lA[r][kg * 8]) =
        *reinterpret_cast<const uint4*>(A + (rowA0 + r) * DD + kg * 8);
  }
  for (int i = 0; i < 4; ++i) {
    int f = tid + i * 256;
    int r = f >> 4, kg = f & 15;
    *reinterpret_cast<uint4*>(&lB[r][kg * 8]) =
        *reinterpret_cast<const uint4*>(Bt + (rowB0 + r) * DD + kg * 8);
  }
  __syncthreads();
  int wave = tid >> 6, lane = tid & 63;
  int wm = (wave >> 1) * 64;
  int wn = (wave & 1) * 32;
  int quad = lane >> 4, l16 = lane & 15;
  f32x4 acc[4][2];
  #pragma unroll
  for (int mi = 0; mi < 4; ++mi)
    #pragma unroll
    for (int ni = 0; ni < 2; ++ni) acc[mi][ni] = {0.f, 0.f, 0.f, 0.f};
  #pragma unroll
  for (int ks = 0; ks < 4; ++ks) {
    int kb = ks * 32 + quad * 8;
    bf16x8 af[4], bfr[2];
    #pragma unroll
    for (int mi = 0; mi < 4; ++mi)
      af[mi] = *reinterpret_cast<const bf16x8*>(&lA[wm + mi * 16 + l16][kb]);
    #pragma unroll
    for (int ni = 0; ni < 2; ++ni)
      bfr[ni] = *reinterpret_cast<const bf16x8*>(&lB[wn + ni * 16 + l16][kb]);
    #pragma unroll
    for (int mi = 0; mi < 4; ++mi)
      #pragma unroll
      for (int ni = 0; ni < 2; ++ni)
        acc[mi][ni] = __builtin_amdgcn_mfma_f32_16x16x32_bf16(af[mi], bfr[ni], acc[mi][ni], 0, 0, 0);
  }
  #pragma unroll
  for (int mi = 0; mi < 4; ++mi)
    #pragma unroll
    for (int ni = 0; ni < 2; ++ni)
      #pragma unroll
      for (int r = 0; r < 4; ++r) {
        long row = rowA0 + wm + mi * 16 + quad * 4 + r;
        long col = rowB0 + wn + ni * 16 + l16;
        bf16 v = __float2bfloat16(acc[mi][ni][r]);
        if (transC) C[col * (long)ldc + row] = v;
        else        C[row * (long)ldc + col] = v;
        if (Cr)     Cr[row * DD + col] = v;
      }
}

// ---------------- per-row exact top-k threshold + rowsum ----------------
// Radix binary search on order-preserving u16 keys of bf16; per-candidate count
// via direct wave-mask compare (1 v_cmp) + scalar popcount/accumulate.
__launch_bounds__(256)
__global__ void topk_thresh(const bf16* __restrict__ S, unsigned short* __restrict__ kthr,
                            float* __restrict__ invRsF) {
  __shared__ int red[2][4];
  __shared__ float sred[4];
  int tid = threadIdx.x;
  int wave = tid >> 6, lane = tid & 63;
  long base = (long)blockIdx.x * NN;
  int keys[32];
  #pragma unroll
  for (int i = 0; i < 4; ++i) {
    int f = tid + i * 256;
    uint4 v = *reinterpret_cast<const uint4*>(S + base + (long)f * 8);
    const unsigned short* p = reinterpret_cast<const unsigned short*>(&v);
    #pragma unroll
    for (int e = 0; e < 8; ++e) {
      unsigned short u = p[e];
      keys[i * 8 + e] = (u & 0x8000) ? (unsigned short)~u : (unsigned short)(u | 0x8000);
    }
  }
  int cur = 0;
  #pragma unroll
  for (int bit = 15; bit >= 0; --bit) {
    int cand = cur | (1 << bit);
    int c = 0;
    #pragma unroll
    for (int i = 0; i < 32; ++i)
      c += (int)__popcll((unsigned long long)WAVE_GE_MASK(keys[i], cand));
    int buf = bit & 1;                 // double buffer -> one barrier per iteration
    if (lane == 0) red[buf][wave] = c; // c is wave-uniform
    __syncthreads();
    int tot = red[buf][0] + red[buf][1] + red[buf][2] + red[buf][3];
    if (tot >= KTOP) cur = cand;
  }
  float sum = 0.f;
  #pragma unroll
  for (int i = 0; i < 32; ++i) {
    int k = keys[i];
    if (k >= cur) {
      unsigned short u = (k & 0x8000) ? (unsigned short)(k ^ 0x8000) : (unsigned short)~k;
      sum += __uint_as_float(((unsigned int)u) << 16);
    }
  }
  for (int off = 1; off < 64; off <<= 1) sum += __shfl_xor(sum, off);
  if (lane == 0) sred[wave] = sum;
  __syncthreads();
  if (tid == 0) {
    invRsF[blockIdx.x] = 1.0f / (sred[0] + sred[1] + sred[2] + sred[3] + 1.0f);
    kthr[blockIdx.x] = (unsigned short)cur;
  }
}

// ---------------- split-K masked AV GEMM: Pacc[s] = (mask(S) @ Y2) over k-slice s ----
__launch_bounds__(256)
__global__ void fused_av_partial(const bf16* __restrict__ S, const bf16* __restrict__ Yt2,
                                 const unsigned short* __restrict__ kthr,
                                 float* __restrict__ Pacc) {
  __shared__ bf16 lAf[32][72];
  __shared__ bf16 lY2[128][72];
  int tid = threadIdx.x;
  long row0 = (long)blockIdx.x * 32;
  long kbase = (long)blockIdx.y * KCH;
  int wave = tid >> 6, lane = tid & 63;
  int wm = (wave >> 1) * 16;   // 0 / 16
  int wn = (wave & 1) * 64;    // 0 / 64
  int quad = lane >> 4, l16 = lane & 15;
  int sr = tid >> 3, skg = tid & 7;          // staging coords: row, k-group
  int tk = kthr[row0 + sr];                  // per-thread row threshold key
  const bf16* srow = S + (row0 + sr) * (long)NN + kbase + skg * 8;
  f32x4 accF[4];
  #pragma unroll
  for (int ni = 0; ni < 4; ++ni) accF[ni] = {0.f, 0.f, 0.f, 0.f};
  for (int k0 = 0; k0 < KCH; k0 += 64) {
    __syncthreads();
    {
      uint4 v = *reinterpret_cast<const uint4*>(srow + k0);
      const unsigned short* p = reinterpret_cast<const unsigned short*>(&v);
      unsigned short m[8];
      #pragma unroll
      for (int e = 0; e < 8; ++e) {
        unsigned short u = p[e];
        int key = (u & 0x8000) ? (unsigned short)~u : (unsigned short)(u | 0x8000);
        m[e] = (key >= tk) ? u : (unsigned short)0;
      }
      *reinterpret_cast<uint4*>(&lAf[sr][skg * 8]) = *reinterpret_cast<const uint4*>(m);
    }
    for (int i = 0; i < 4; ++i) {       // 128 cols x 8 uint4
      int f = tid + i * 256;
      int c = f >> 3, kg = f & 7;
      *reinterpret_cast<uint4*>(&lY2[c][kg * 8]) =
          *reinterpret_cast<const uint4*>(Yt2 + (long)c * NN + kbase + k0 + kg * 8);
    }
    __syncthreads();
    #pragma unroll
    for (int ks = 0; ks < 2; ++ks) {
      int kb = ks * 32 + quad * 8;
      bf16x8 afm = *reinterpret_cast<const bf16x8*>(&lAf[wm + l16][kb]);
      #pragma unroll
      for (int ni = 0; ni < 4; ++ni) {
        bf16x8 b2 = *reinterpret_cast<const bf16x8*>(&lY2[wn + ni * 16 + l16][kb]);
        accF[ni] = __builtin_amdgcn_mfma_f32_16x16x32_bf16(afm, b2, accF[ni], 0, 0, 0);
      }
    }
  }
  float* out = Pacc + ((long)blockIdx.y * NN) * DD;
  #pragma unroll
  for (int ni = 0; ni < 4; ++ni)
    #pragma unroll
    for (int r = 0; r < 4; ++r) {
      long row = row0 + wm + quad * 4 + r;
      int col = wn + ni * 16 + l16;
      out[row * DD + col] = accF[ni][r];
    }
}

// ---------------- epilogue: reduce partials + prior + eye + leaky (+ optional final) ----
// If outf != nullptr: writes outf = v + hres*imp (final residual) instead of Xout.
__global__ void epilogue(const float* __restrict__ Pacc, const bf16* __restrict__ Yr1,
                         const bf16* __restrict__ Yr2, const float* __restrict__ pvec,
                         const float* __restrict__ Mt, const float* __restrict__ invRsF,
                         float* __restrict__ Xout, const float* __restrict__ hres,
                         const float* __restrict__ impf, float* __restrict__ outf) {
  int i = blockIdx.x * 256 + threadIdx.x;
  int row = i >> 7, col = i & 127;
  float acc = 0.f;
  #pragma unroll
  for (int s = 0; s < KSLICE; ++s) acc += Pacc[((long)s * NN + row) * DD + col];
  const float* pv = pvec + row * 8;
  float y1 = __bfloat162float(Yr1[i]);
  float y2 = __bfloat162float(Yr2[i]);
  float prior = pv[5] * y1 + pv[0] * Mt[col] + pv[1] * Mt[128 + col] + pv[2] * Mt[256 + col]
              + pv[3] * Mt[384 + col] + pv[4] * Mt[512 + col];
  float v = prior + invRsF[row] * (acc + y2);
  v = v > 0.f ? v : 0.01f * v;
  if (outf) outf[i] = v + hres[i] * impf[row];
  else      Xout[i] = v;
}

// ---------------- host ----------------

extern "C" void kernel_launch(void* const* d_in, const int* in_sizes, int n_in,
                              void* d_out, int out_size, void* d_ws, size_t ws_size,
                              hipStream_t stream) {
  const void* x_in   = d_in[0];
  const void* imp_in = d_in[1];
  const void* W1 = d_in[2];
  const void* W2 = d_in[3];
  float* out = (float*)d_out;

  char* ws = (char*)d_ws;
  size_t o = 0;
  auto alloc = [&](size_t bytes) { void* p = ws + o; o += (bytes + 511) & ~511ull; return p; };
  bf16*  Af   = (bf16*)alloc((size_t)NN * NN * 2);    // 134 MB raw similarity S
  float* Pacc = (float*)alloc((size_t)KSLICE * NN * DD * 4);  // 16 MB split-K partials
  float* xf0  = (float*)alloc((size_t)NN * DD * 4);
  float* xf1  = (float*)alloc((size_t)NN * DD * 4);
  bf16*  xnb  = (bf16*)alloc((size_t)NN * DD * 2);
  bf16*  xb   = (bf16*)alloc((size_t)NN * DD * 2);
  bf16*  Yt1  = (bf16*)alloc((size_t)NN * DD * 2);    // [128][8192] (x@W1)^T
  bf16*  Yt2  = (bf16*)alloc((size_t)NN * DD * 2);
  bf16*  Yr1  = (bf16*)alloc((size_t)NN * DD * 2);    // [8192][128] row-major copies
  bf16*  Yr2  = (bf16*)alloc((size_t)NN * DD * 2);
  bf16*  Wt1  = (bf16*)alloc((size_t)2 * DD * DD * 2);
  bf16*  Wt2  = (bf16*)alloc((size_t)2 * DD * DD * 2);
  float* impf = (float*)alloc((size_t)NN * 4);
  float* pvec = (float*)alloc((size_t)NN * 8 * 4);
  float* Mt   = (float*)alloc((size_t)5 * 128 * 4);
  float* Gt   = (float*)alloc((size_t)8 * 4);
  float* invRsF = (float*)alloc((size_t)NN * 4);
  unsigned short* kthr = (unsigned short*)alloc((size_t)NN * 2);
  int*   dflag  = (int*)alloc(64);
  (void)ws_size; (void)n_in; (void)in_sizes; (void)out_size;

  detect_dtype<<<1, 256, 0, stream>>>((const unsigned short*)x_in, dflag);
  prep<<<4101, 256, 0, stream>>>(x_in, imp_in, W1, W2, xf0, impf, Wt1, Wt2, dflag);

  float* xcur = xf0;
  for (int l = 0; l < 2; ++l) {
    float* xnxt = (l == 0) ? xf1 : xf0;
    rownorm<<<NN / 4, 256, 0, stream>>>(xcur, xnb, xb);
    gemm_k128<<<dim3(2, 64), 256, 0, stream>>>(xb, Wt1 + l * DD * DD, Yt1, NN, 1, Yr1);
    gemm_k128<<<dim3(2, 64), 256, 0, stream>>>(xb, Wt2 + l * DD * DD, Yt2, NN, 1, Yr2);
    prior_reduce<<<129, 256, 0, stream>>>(impf, Yt1, Mt, Gt);
    prior_vec<<<NN / 256, 256, 0, stream>>>(impf, Gt, pvec);
    gemm_k128<<<dim3(NN / 64, NN / 128), 256, 0, stream>>>(xnb, xnb, Af, NN, 0, nullptr);
    topk_thresh<<<NN, 256, 0, stream>>>(Af, kthr, invRsF);
    fused_av_partial<<<dim3(NN / 32, KSLICE), 256, 0, stream>>>(Af, Yt2, kthr, Pacc);
    if (l == 0)
      epilogue<<<NN * DD / 256, 256, 0, stream>>>(Pacc, Yr1, Yr2, pvec, Mt, invRsF,
                                                  xnxt, nullptr, nullptr, nullptr);
    else
      epilogue<<<NN * DD / 256, 256, 0, stream>>>(Pacc, Yr1, Yr2, pvec, Mt, invRsF,
                                                  nullptr, xf1, impf, out);
    xcur = xnxt;
  }
}

// Round 9
// 492.247 us; speedup vs baseline: 3.7540x; 1.0046x over previous
//
#include <hip/hip_runtime.h>
#include <hip/hip_bf16.h>

typedef __bf16 bf16x8 __attribute__((ext_vector_type(8)));
typedef float f32x4 __attribute__((ext_vector_type(4)));
typedef __hip_bfloat16 bf16;

static constexpr int NN = 8192;
static constexpr int DD = 128;
static constexpr int KTOP = 1638;   // int(0.2 * 8192)
static constexpr int KSLICE = 4;    // split-K factor for the AV GEMM
static constexpr int KCH = NN / KSLICE;

// ---------------- input dtype detection ----------------
__global__ void detect_dtype(const unsigned short* __restrict__ xin, int* __restrict__ flag) {
  __shared__ int cnt;
  if (threadIdx.x == 0) cnt = 0;
  __syncthreads();
  int c = 0;
  for (int i = threadIdx.x; i < 4096; i += 256) {
    int e = (xin[i] >> 7) & 0xFF;
    if (e >= 0x8A) ++c;
  }
  atomicAdd(&cnt, c);
  __syncthreads();
  if (threadIdx.x == 0) *flag = (cnt > 16) ? 1 : 0;
}

// ---------------- merged prep: cvt x, cvt imp, transpose W (dual dtype) ----------------
__global__ void prep(const void* __restrict__ x_in, const void* __restrict__ imp_in,
                     const void* __restrict__ W1, const void* __restrict__ W2,
                     float* __restrict__ xf, float* __restrict__ impf,
                     bf16* __restrict__ Wt1, bf16* __restrict__ Wt2,
                     const int* __restrict__ flag) {
  int isf32 = *flag;
  int b = blockIdx.x;
  if (b < 4096) {
    int i = b * 256 + threadIdx.x;
    xf[i] = isf32 ? ((const float*)x_in)[i] : __bfloat162float(((const bf16*)x_in)[i]);
  } else if (b == 4096) {
    for (int i = threadIdx.x; i < NN; i += 256)
      impf[i] = isf32 ? ((const float*)imp_in)[i] : __bfloat162float(((const bf16*)imp_in)[i]);
  } else {
    int w = b - 4097;                 // 0,1 -> W1 l=0,1 ; 2,3 -> W2 l=0,1
    const void* srcv = (w < 2 ? W1 : W2);
    bf16* dst = (w < 2 ? Wt1 : Wt2) + (w & 1) * DD * DD;
    int off = (w & 1) * DD * DD;
    for (int f = threadIdx.x; f < DD * DD; f += 256) {
      int n = f >> 7, k = f & 127;
      float v = isf32 ? ((const float*)srcv)[off + k * DD + n]
                      : __bfloat162float(((const bf16*)srcv)[off + k * DD + n]);
      dst[n * DD + k] = __float2bfloat16(v);
    }
  }
}

// per-row L2 normalize -> xnb (bf16), plus plain bf16 cast -> xb
__global__ void rownorm(const float* __restrict__ xf, bf16* __restrict__ xnb, bf16* __restrict__ xb) {
  int wave = threadIdx.x >> 6;
  int lane = threadIdx.x & 63;
  int row = blockIdx.x * 4 + wave;
  const float* xr = xf + (long)row * DD;
  float2 v = reinterpret_cast<const float2*>(xr)[lane];
  float s = v.x * v.x + v.y * v.y;
  for (int off = 1; off < 64; off <<= 1) s += __shfl_xor(s, off);
  float inv = 1.0f / (sqrtf(s) + 1e-8f);
  int c = lane * 2;
  xb[(long)row * DD + c]      = __float2bfloat16(v.x);
  xb[(long)row * DD + c + 1]  = __float2bfloat16(v.y);
  xnb[(long)row * DD + c]     = __float2bfloat16(v.x * inv);
  xnb[(long)row * DD + c + 1] = __float2bfloat16(v.y * inv);
}

// ---------------- rank-5 factorized Gaussian prior ----------------
// P_ij = exp(-(di-dj)^2/32) = a_i a_j exp(di dj/16); 5-term Taylor of exp(z), z<=1/16.
__launch_bounds__(256)
__global__ void prior_reduce(const float* __restrict__ impf, const bf16* __restrict__ Yt1,
                             float* __restrict__ Mt, float* __restrict__ Gt) {
  __shared__ float red[5][4];
  int c = blockIdx.x;
  int tid = threadIdx.x;
  float s[5] = {0.f, 0.f, 0.f, 0.f, 0.f};
  bool hasY = (c < 128);
  const bf16* col = Yt1 + (long)(hasY ? c : 0) * NN;
  for (int j = tid; j < NN; j += 256) {
    float d = impf[j];
    float a = __expf(d * d * (-1.0f / 32.0f));
    float p = hasY ? a * __bfloat162float(col[j]) : a;
    #pragma unroll
    for (int t = 0; t < 5; ++t) { s[t] += p; p *= d; }
  }
  #pragma unroll
  for (int t = 0; t < 5; ++t)
    for (int off = 1; off < 64; off <<= 1) s[t] += __shfl_xor(s[t], off);
  int wave = tid >> 6, lane = tid & 63;
  if (lane == 0)
    #pragma unroll
    for (int t = 0; t < 5; ++t) red[t][wave] = s[t];
  __syncthreads();
  if (tid == 0) {
    #pragma unroll
    for (int t = 0; t < 5; ++t) {
      float v = red[t][0] + red[t][1] + red[t][2] + red[t][3];
      if (hasY) Mt[t * 128 + c] = v; else Gt[t] = v;
    }
  }
}

__global__ void prior_vec(const float* __restrict__ impf, const float* __restrict__ Gt,
                          float* __restrict__ pvec) {
  int i = blockIdx.x * 256 + threadIdx.x;
  float d = impf[i];
  float a = __expf(d * d * (-1.0f / 32.0f));
  const float ct[5] = {1.0f, 1.0f / 16.0f, 1.0f / 512.0f, 1.0f / 24576.0f, 1.0f / 1572864.0f};
  float g[5];
  float p = a;
  #pragma unroll
  for (int t = 0; t < 5; ++t) { g[t] = ct[t] * p; p *= d; }
  float rs = 1.0f;  // + eye
  #pragma unroll
  for (int t = 0; t < 5; ++t) rs += g[t] * Gt[t];
  float inv = 1.0f / rs;
  #pragma unroll
  for (int t = 0; t < 5; ++t) pvec[i * 8 + t] = g[t] * inv;
  pvec[i * 8 + 5] = inv;
}

// ---------------- K=128 GEMM (MFMA): C = A @ Bt^T ----------------
// transC: writes C[n][m] (ldc = NN). Cr (optional): row-major copy C[m][n], ld = DD.
__launch_bounds__(256)
__global__ void gemm_k128(const bf16* __restrict__ A, const bf16* __restrict__ Bt,
                          bf16* __restrict__ C, int ldc, int transC, bf16* __restrict__ Cr) {
  __shared__ bf16 lA[128][136];
  __shared__ bf16 lB[64][136];
  int tid = threadIdx.x;
  long rowA0 = (long)blockIdx.y * 128;
  long rowB0 = (long)blockIdx.x * 64;
  for (int i = 0; i < 8; ++i) {
    int f = tid + i * 256;
    int r = f >> 4, kg = f & 15;
    *reinterpret_cast<uint4*>(&lA[r][kg * 8]) =
        *reinterpret_cast<const uint4*>(A + (rowA0 + r) * DD + kg * 8);
  }
  for (int i = 0; i < 4; ++i) {
    int f = tid + i * 256;
    int r = f >> 4, kg = f & 15;
    *reinterpret_cast<uint4*>(&lB[r][kg * 8]) =
        *reinterpret_cast<const uint4*>(Bt + (rowB0 + r) * DD + kg * 8);
  }
  __syncthreads();
  int wave = tid >> 6, lane = tid & 63;
  int wm = (wave >> 1) * 64;
  int wn = (wave & 1) * 32;
  int quad = lane >> 4, l16 = lane & 15;
  f32x4 acc[4][2];
  #pragma unroll
  for (int mi = 0; mi < 4; ++mi)
    #pragma unroll
    for (int ni = 0; ni < 2; ++ni) acc[mi][ni] = {0.f, 0.f, 0.f, 0.f};
  #pragma unroll
  for (int ks = 0; ks < 4; ++ks) {
    int kb = ks * 32 + quad * 8;
    bf16x8 af[4], bfr[2];
    #pragma unroll
    for (int mi = 0; mi < 4; ++mi)
      af[mi] = *reinterpret_cast<const bf16x8*>(&lA[wm + mi * 16 + l16][kb]);
    #pragma unroll
    for (int ni = 0; ni < 2; ++ni)
      bfr[ni] = *reinterpret_cast<const bf16x8*>(&lB[wn + ni * 16 + l16][kb]);
    #pragma unroll
    for (int mi = 0; mi < 4; ++mi)
      #pragma unroll
      for (int ni = 0; ni < 2; ++ni)
        acc[mi][ni] = __builtin_amdgcn_mfma_f32_16x16x32_bf16(af[mi], bfr[ni], acc[mi][ni], 0, 0, 0);
  }
  #pragma unroll
  for (int mi = 0; mi < 4; ++mi)
    #pragma unroll
    for (int ni = 0; ni < 2; ++ni)
      #pragma unroll
      for (int r = 0; r < 4; ++r) {
        long row = rowA0 + wm + mi * 16 + quad * 4 + r;
        long col = rowB0 + wn + ni * 16 + l16;
        bf16 v = __float2bfloat16(acc[mi][ni][r]);
        if (transC) C[col * (long)ldc + row] = v;
        else        C[row * (long)ldc + col] = v;
        if (Cr)     Cr[row * DD + col] = v;
      }
}

// ---------------- per-row exact top-k threshold + rowsum ----------------
// Radix binary search on order-preserving u16 keys of bf16. The per-candidate
// count is pinned to 1 VALU + 2 SALU per key via inline asm:
//   v_cmp_ge_u32 s[d:d+1], v_key, s_cand   (VOP3c, SGPR-pair dest, uniform)
// so popcount+accumulate lower to s_bcnt1_i32_b64 / s_add_i32 on the scalar pipe.
__launch_bounds__(256)
__global__ void topk_thresh(const bf16* __restrict__ S, unsigned short* __restrict__ kthr,
                            float* __restrict__ invRsF) {
  __shared__ int red[2][4];
  __shared__ float sred[4];
  int tid = threadIdx.x;
  int wave = tid >> 6, lane = tid & 63;
  long base = (long)blockIdx.x * NN;
  unsigned keys[32];
  #pragma unroll
  for (int i = 0; i < 4; ++i) {
    int f = tid + i * 256;
    uint4 v = *reinterpret_cast<const uint4*>(S + base + (long)f * 8);
    const unsigned short* p = reinterpret_cast<const unsigned short*>(&v);
    #pragma unroll
    for (int e = 0; e < 8; ++e) {
      unsigned short u = p[e];
      keys[i * 8 + e] = (u & 0x8000) ? (unsigned)(unsigned short)~u
                                     : (unsigned)(u | 0x8000);
    }
  }
  unsigned cur = 0;
  #pragma unroll
  for (int bit = 15; bit >= 0; --bit) {
    unsigned cand = cur | (1u << bit);
    int c = 0;
    #pragma unroll
    for (int i = 0; i < 32; ++i) {
      unsigned long long m;
      asm("v_cmp_ge_u32 %0, %1, %2" : "=s"(m) : "v"(keys[i]), "s"(cand));
      c += (int)__builtin_popcountll(m);
    }
    int buf = bit & 1;                 // double buffer -> one barrier per iteration
    if (lane == 0) red[buf][wave] = c; // c is wave-uniform
    __syncthreads();
    int tot = red[buf][0] + red[buf][1] + red[buf][2] + red[buf][3];
    if (tot >= KTOP) cur = cand;
  }
  float sum = 0.f;
  #pragma unroll
  for (int i = 0; i < 32; ++i) {
    unsigned k = keys[i];
    if (k >= cur) {
      unsigned short u = (k & 0x8000u) ? (unsigned short)(k ^ 0x8000u) : (unsigned short)~k;
      sum += __uint_as_float(((unsigned int)u) << 16);
    }
  }
  for (int off = 1; off < 64; off <<= 1) sum += __shfl_xor(sum, off);
  if (lane == 0) sred[wave] = sum;
  __syncthreads();
  if (tid == 0) {
    invRsF[blockIdx.x] = 1.0f / (sred[0] + sred[1] + sred[2] + sred[3] + 1.0f);
    kthr[blockIdx.x] = (unsigned short)cur;
  }
}

// ---------------- split-K masked AV GEMM: Pacc[s] = (mask(S) @ Y2) over k-slice s ----
__launch_bounds__(256)
__global__ void fused_av_partial(const bf16* __restrict__ S, const bf16* __restrict__ Yt2,
                                 const unsigned short* __restrict__ kthr,
                                 float* __restrict__ Pacc) {
  __shared__ bf16 lAf[32][72];
  __shared__ bf16 lY2[128][72];
  int tid = threadIdx.x;
  long row0 = (long)blockIdx.x * 32;
  long kbase = (long)blockIdx.y * KCH;
  int wave = tid >> 6, lane = tid & 63;
  int wm = (wave >> 1) * 16;   // 0 / 16
  int wn = (wave & 1) * 64;    // 0 / 64
  int quad = lane >> 4, l16 = lane & 15;
  int sr = tid >> 3, skg = tid & 7;          // staging coords: row, k-group
  int tk = kthr[row0 + sr];                  // per-thread row threshold key
  const bf16* srow = S + (row0 + sr) * (long)NN + kbase + skg * 8;
  f32x4 accF[4];
  #pragma unroll
  for (int ni = 0; ni < 4; ++ni) accF[ni] = {0.f, 0.f, 0.f, 0.f};
  for (int k0 = 0; k0 < KCH; k0 += 64) {
    __syncthreads();
    {
      uint4 v = *reinterpret_cast<const uint4*>(srow + k0);
      const unsigned short* p = reinterpret_cast<const unsigned short*>(&v);
      unsigned short m[8];
      #pragma unroll
      for (int e = 0; e < 8; ++e) {
        unsigned short u = p[e];
        int key = (u & 0x8000) ? (unsigned short)~u : (unsigned short)(u | 0x8000);
        m[e] = (key >= tk) ? u : (unsigned short)0;
      }
      *reinterpret_cast<uint4*>(&lAf[sr][skg * 8]) = *reinterpret_cast<const uint4*>(m);
    }
    for (int i = 0; i < 4; ++i) {       // 128 cols x 8 uint4
      int f = tid + i * 256;
      int c = f >> 3, kg = f & 7;
      *reinterpret_cast<uint4*>(&lY2[c][kg * 8]) =
          *reinterpret_cast<const uint4*>(Yt2 + (long)c * NN + kbase + k0 + kg * 8);
    }
    __syncthreads();
    #pragma unroll
    for (int ks = 0; ks < 2; ++ks) {
      int kb = ks * 32 + quad * 8;
      bf16x8 afm = *reinterpret_cast<const bf16x8*>(&lAf[wm + l16][kb]);
      #pragma unroll
      for (int ni = 0; ni < 4; ++ni) {
        bf16x8 b2 = *reinterpret_cast<const bf16x8*>(&lY2[wn + ni * 16 + l16][kb]);
        accF[ni] = __builtin_amdgcn_mfma_f32_16x16x32_bf16(afm, b2, accF[ni], 0, 0, 0);
      }
    }
  }
  float* out = Pacc + ((long)blockIdx.y * NN) * DD;
  #pragma unroll
  for (int ni = 0; ni < 4; ++ni)
    #pragma unroll
    for (int r = 0; r < 4; ++r) {
      long row = row0 + wm + quad * 4 + r;
      int col = wn + ni * 16 + l16;
      out[row * DD + col] = accF[ni][r];
    }
}

// ---------------- epilogue: reduce partials + prior + eye + leaky (+ optional final) ----
// If outf != nullptr: writes outf = v + hres*imp (final residual) instead of Xout.
__global__ void epilogue(const float* __restrict__ Pacc, const bf16* __restrict__ Yr1,
                         const bf16* __restrict__ Yr2, const float* __restrict__ pvec,
                         const float* __restrict__ Mt, const float* __restrict__ invRsF,
                         float* __restrict__ Xout, const float* __restrict__ hres,
                         const float* __restrict__ impf, float* __restrict__ outf) {
  int i = blockIdx.x * 256 + threadIdx.x;
  int row = i >> 7, col = i & 127;
  float acc = 0.f;
  #pragma unroll
  for (int s = 0; s < KSLICE; ++s) acc += Pacc[((long)s * NN + row) * DD + col];
  const float* pv = pvec + row * 8;
  float y1 = __bfloat162float(Yr1[i]);
  float y2 = __bfloat162float(Yr2[i]);
  float prior = pv[5] * y1 + pv[0] * Mt[col] + pv[1] * Mt[128 + col] + pv[2] * Mt[256 + col]
              + pv[3] * Mt[384 + col] + pv[4] * Mt[512 + col];
  float v = prior + invRsF[row] * (acc + y2);
  v = v > 0.f ? v : 0.01f * v;
  if (outf) outf[i] = v + hres[i] * impf[row];
  else      Xout[i] = v;
}

// ---------------- host ----------------

extern "C" void kernel_launch(void* const* d_in, const int* in_sizes, int n_in,
                              void* d_out, int out_size, void* d_ws, size_t ws_size,
                              hipStream_t stream) {
  const void* x_in   = d_in[0];
  const void* imp_in = d_in[1];
  const void* W1 = d_in[2];
  const void* W2 = d_in[3];
  float* out = (float*)d_out;

  char* ws = (char*)d_ws;
  size_t o = 0;
  auto alloc = [&](size_t bytes) { void* p = ws + o; o += (bytes + 511) & ~511ull; return p; };
  bf16*  Af   = (bf16*)alloc((size_t)NN * NN * 2);    // 134 MB raw similarity S
  float* Pacc = (float*)alloc((size_t)KSLICE * NN * DD * 4);  // 16 MB split-K partials
  float* xf0  = (float*)alloc((size_t)NN * DD * 4);
  float* xf1  = (float*)alloc((size_t)NN * DD * 4);
  bf16*  xnb  = (bf16*)alloc((size_t)NN * DD * 2);
  bf16*  xb   = (bf16*)alloc((size_t)NN * DD * 2);
  bf16*  Yt1  = (bf16*)alloc((size_t)NN * DD * 2);    // [128][8192] (x@W1)^T
  bf16*  Yt2  = (bf16*)alloc((size_t)NN * DD * 2);
  bf16*  Yr1  = (bf16*)alloc((size_t)NN * DD * 2);    // [8192][128] row-major copies
  bf16*  Yr2  = (bf16*)alloc((size_t)NN * DD * 2);
  bf16*  Wt1  = (bf16*)alloc((size_t)2 * DD * DD * 2);
  bf16*  Wt2  = (bf16*)alloc((size_t)2 * DD * DD * 2);
  float* impf = (float*)alloc((size_t)NN * 4);
  float* pvec = (float*)alloc((size_t)NN * 8 * 4);
  float* Mt   = (float*)alloc((size_t)5 * 128 * 4);
  float* Gt   = (float*)alloc((size_t)8 * 4);
  float* invRsF = (float*)alloc((size_t)NN * 4);
  unsigned short* kthr = (unsigned short*)alloc((size_t)NN * 2);
  int*   dflag  = (int*)alloc(64);
  (void)ws_size; (void)n_in; (void)in_sizes; (void)out_size;

  detect_dtype<<<1, 256, 0, stream>>>((const unsigned short*)x_in, dflag);
  prep<<<4101, 256, 0, stream>>>(x_in, imp_in, W1, W2, xf0, impf, Wt1, Wt2, dflag);

  float* xcur = xf0;
  for (int l = 0; l < 2; ++l) {
    float* xnxt = (l == 0) ? xf1 : xf0;
    rownorm<<<NN / 4, 256, 0, stream>>>(xcur, xnb, xb);
    gemm_k128<<<dim3(2, 64), 256, 0, stream>>>(xb, Wt1 + l * DD * DD, Yt1, NN, 1, Yr1);
    gemm_k128<<<dim3(2, 64), 256, 0, stream>>>(xb, Wt2 + l * DD * DD, Yt2, NN, 1, Yr2);
    prior_reduce<<<129, 256, 0, stream>>>(impf, Yt1, Mt, Gt);
    prior_vec<<<NN / 256, 256, 0, stream>>>(impf, Gt, pvec);
    gemm_k128<<<dim3(NN / 64, NN / 128), 256, 0, stream>>>(xnb, xnb, Af, NN, 0, nullptr);
    topk_thresh<<<NN, 256, 0, stream>>>(Af, kthr, invRsF);
    fused_av_partial<<<dim3(NN / 32, KSLICE), 256, 0, stream>>>(Af, Yt2, kthr, Pacc);
    if (l == 0)
      epilogue<<<NN * DD / 256, 256, 0, stream>>>(Pacc, Yr1, Yr2, pvec, Mt, invRsF,
                                                  xnxt, nullptr, nullptr, nullptr);
    else
      epilogue<<<NN * DD / 256, 256, 0, stream>>>(Pacc, Yr1, Yr2, pvec, Mt, invRsF,
                                                  nullptr, xf1, impf, out);
    xcur = xnxt;
  }
}